// Round 1
// baseline (590.912 us; speedup 1.0000x reference)
//
#include <hip/hip_runtime.h>

// ---------------- constants for this problem ----------------
#define EBD   512      // embed size (= head dim here)
#define NHEAD 8
#define BSZ   4
#define SEQ   1024
#define MTOK  4096     // B*S tokens
#define HE    4096     // H*E
#define FFD   2048     // 4*E

typedef __bf16 bf16;
typedef __attribute__((ext_vector_type(8))) __bf16 bf16x8;
typedef __attribute__((ext_vector_type(4))) float  f32x4;

// async global->LDS, 16B per lane; LDS dest must be wave-uniform base + lane*16
__device__ __forceinline__ void async_load16(const void* g, void* l) {
  __builtin_amdgcn_global_load_lds(
      (const __attribute__((address_space(1))) void*)g,
      (__attribute__((address_space(3))) void*)l, 16, 0, 0);
}

// ---------------- GEMM: C = A @ Bt^T  (A: MxK row-major, Bt: NxK row-major) ----------------
// 128x128 tile, BK=32, 256 threads (4 waves, each 64x64 via 4x4 of 16x16x32 MFMA).
// Batched via blockIdx.z with (b,h)-decomposed strides: off = (z>>3)*bXb + (z&7)*bXh.
// Epilogue: v = acc*scale + bias[col] + res[row*ldr+col]; optional relu; store f32 and/or bf16.
__global__ void gemm_bt(const bf16* __restrict__ A, const bf16* __restrict__ Bt,
                        float* __restrict__ outF, bf16* __restrict__ outB,
                        const float* __restrict__ bias, const float* __restrict__ res,
                        int lda, int ldb, int ldc, int ldr, int K,
                        long long bAb, long long bAh, long long bBb, long long bBh,
                        long long bCb, long long bCh,
                        float scale, int relu)
{
  __shared__ __attribute__((aligned(16))) bf16 As[128 * 32];
  __shared__ __attribute__((aligned(16))) bf16 Bs[128 * 32];

  const int t = threadIdx.x;
  const int w = t >> 6, l = t & 63;
  const int m0 = blockIdx.y * 128, n0 = blockIdx.x * 128;
  const int z = blockIdx.z, zb = z >> 3, zh = z & 7;

  const bf16* Ab = A + (size_t)zb * bAb + (size_t)zh * bAh;
  const bf16* Bb = Bt + (size_t)zb * bBb + (size_t)zh * bBh;

  // staging map: thread t handles 16B chunks t and t+256 of each 128x32 tile
  const int srow = t >> 2;            // rows 0..63 (+64 for second chunk)
  const int skc  = (t & 3) * 8;       // k element offset (8 bf16 = 16B)
  const bf16* pA = Ab + (size_t)(m0 + srow) * lda + skc;
  const bf16* pB = Bb + (size_t)(n0 + srow) * ldb + skc;
  const size_t ldA64 = (size_t)64 * lda;
  const size_t ldB64 = (size_t)64 * ldb;

  bf16* ldsA0 = As + w * 512;          // wave-uniform bases (lane*16B added by HW)
  bf16* ldsA1 = As + 2048 + w * 512;
  bf16* ldsB0 = Bs + w * 512;
  bf16* ldsB1 = Bs + 2048 + w * 512;

  const int wm = (w >> 1) * 64, wn = (w & 1) * 64;
  const int lr = l & 15;               // A-row / B-col within 16
  const int lk = (l >> 4) * 8;         // k chunk within 32

  f32x4 acc[4][4];
#pragma unroll
  for (int i = 0; i < 4; ++i)
#pragma unroll
    for (int j = 0; j < 4; ++j) { f32x4 zv = {0.f, 0.f, 0.f, 0.f}; acc[i][j] = zv; }

  const int nkt = K >> 5;
  for (int kt = 0; kt < nkt; ++kt) {
    __syncthreads();                   // previous iteration's ds_reads done
    async_load16(pA, ldsA0);
    async_load16(pA + ldA64, ldsA1);
    async_load16(pB, ldsB0);
    async_load16(pB + ldB64, ldsB1);
    pA += 32; pB += 32;
    __syncthreads();                   // staging complete (vmcnt drained)
    bf16x8 af[4], bv[4];
#pragma unroll
    for (int i = 0; i < 4; ++i)
      af[i] = *(const bf16x8*)&As[(wm + i * 16 + lr) * 32 + lk];
#pragma unroll
    for (int i = 0; i < 4; ++i)
      bv[i] = *(const bf16x8*)&Bs[(wn + i * 16 + lr) * 32 + lk];
#pragma unroll
    for (int mi = 0; mi < 4; ++mi)
#pragma unroll
      for (int ni = 0; ni < 4; ++ni)
        acc[mi][ni] = __builtin_amdgcn_mfma_f32_16x16x32_bf16(af[mi], bv[ni], acc[mi][ni], 0, 0, 0);
  }

  // epilogue: C/D layout col=lane&15, row=(lane>>4)*4+r  [measured m89/m91]
  const size_t offC = (size_t)zb * bCb + (size_t)zh * bCh;
  const int rbase = m0 + wm + (l >> 4) * 4;
#pragma unroll
  for (int ni = 0; ni < 4; ++ni) {
    const int colg = n0 + wn + ni * 16 + lr;
    const float bvs = bias ? bias[colg] : 0.0f;
#pragma unroll
    for (int mi = 0; mi < 4; ++mi) {
#pragma unroll
      for (int r = 0; r < 4; ++r) {
        const int rowg = rbase + mi * 16 + r;
        float v = acc[mi][ni][r] * scale + bvs;
        if (res)  v += res[(size_t)rowg * ldr + colg];
        if (relu) v = fmaxf(v, 0.0f);
        const size_t idx = offC + (size_t)rowg * ldc + colg;
        if (outF) outF[idx] = v;
        if (outB) outB[idx] = (bf16)v;
      }
    }
  }
}

// ---------------- cast x (fp32 -> bf16), 4 elems/thread ----------------
__global__ void cast_x_bf16(const float* __restrict__ in, bf16* __restrict__ out, int n4) {
  int i = blockIdx.x * 256 + threadIdx.x;
  if (i >= n4) return;
  float4 v = ((const float4*)in)[i];
  union { bf16 h[4]; float2 f; } u;
  u.h[0] = (bf16)v.x; u.h[1] = (bf16)v.y; u.h[2] = (bf16)v.z; u.h[3] = (bf16)v.w;
  ((float2*)out)[i] = u.f;
}

// ---------------- weight transpose+cast: in fp32 [K][N] -> out bf16 [N][K] ----------------
__global__ void transpose_cast_w(const float* __restrict__ in, bf16* __restrict__ out,
                                 int K, int N) {
  __shared__ float tile[32][33];
  int n0 = blockIdx.x * 32, k0 = blockIdx.y * 32;
  int tx = threadIdx.x, ty = threadIdx.y;
#pragma unroll
  for (int i = 0; i < 32; i += 8)
    tile[ty + i][tx] = in[(size_t)(k0 + ty + i) * N + n0 + tx];
  __syncthreads();
#pragma unroll
  for (int i = 0; i < 32; i += 8)
    out[(size_t)(n0 + ty + i) * K + k0 + tx] = (bf16)tile[tx][ty + i];
}

// ---------------- V transpose: v[b][s][h][e] -> vT[(b,h)][e][s], bf16 ----------------
__global__ void transpose_v(const bf16* __restrict__ v, bf16* __restrict__ vT) {
  int z = blockIdx.z, b = z >> 3, h = z & 7;
  const bf16* in = v + (size_t)b * SEQ * HE + (size_t)h * EBD;
  bf16* out = vT + (size_t)z * EBD * SEQ;
  __shared__ bf16 tile[32][33];
  int e0 = blockIdx.x * 32, s0 = blockIdx.y * 32;
  int tx = threadIdx.x, ty = threadIdx.y;
#pragma unroll
  for (int i = 0; i < 32; i += 8)
    tile[ty + i][tx] = in[(size_t)(s0 + ty + i) * HE + e0 + tx];
  __syncthreads();
#pragma unroll
  for (int i = 0; i < 32; i += 8)
    out[(size_t)(e0 + ty + i) * SEQ + s0 + tx] = tile[tx][ty + i];
}

// ---------------- softmax over rows of 1024 bf16, in-place; one wave per row ----------------
__global__ void softmax_rows(bf16* __restrict__ sc) {
  int l = threadIdx.x & 63, w = threadIdx.x >> 6;
  size_t row = (size_t)blockIdx.x * 4 + w;
  float4* p4 = (float4*)(sc + row * SEQ);
  union U8 { float4 f; bf16 h[8]; };
  U8 u0, u1; u0.f = p4[l]; u1.f = p4[l + 64];
  float v[16];
  float mx = -1e30f;
#pragma unroll
  for (int i = 0; i < 8; ++i) { v[i] = (float)u0.h[i]; mx = fmaxf(mx, v[i]); }
#pragma unroll
  for (int i = 0; i < 8; ++i) { v[8 + i] = (float)u1.h[i]; mx = fmaxf(mx, v[8 + i]); }
#pragma unroll
  for (int d = 1; d < 64; d <<= 1) mx = fmaxf(mx, __shfl_xor(mx, d));
  float s = 0.0f;
#pragma unroll
  for (int i = 0; i < 16; ++i) { v[i] = __expf(v[i] - mx); s += v[i]; }
#pragma unroll
  for (int d = 1; d < 64; d <<= 1) s += __shfl_xor(s, d);
  float inv = 1.0f / s;
#pragma unroll
  for (int i = 0; i < 8; ++i) u0.h[i] = (bf16)(v[i] * inv);
#pragma unroll
  for (int i = 0; i < 8; ++i) u1.h[i] = (bf16)(v[8 + i] * inv);
  p4[l] = u0.f; p4[l + 64] = u1.f;
}

// ---------------- layernorm over rows of 512 fp32; one wave per row ----------------
__global__ void layernorm_rows(const float* __restrict__ in, const float* __restrict__ gw,
                               const float* __restrict__ bw, float* __restrict__ outF,
                               bf16* __restrict__ outB) {
  int l = threadIdx.x & 63, w = threadIdx.x >> 6;
  int row = blockIdx.x * 4 + w;
  const float4* p = (const float4*)(in + (size_t)row * EBD);
  float4 a = p[l], b = p[l + 64];
  float s = a.x + a.y + a.z + a.w + b.x + b.y + b.z + b.w;
  float q = a.x * a.x + a.y * a.y + a.z * a.z + a.w * a.w
          + b.x * b.x + b.y * b.y + b.z * b.z + b.w * b.w;
#pragma unroll
  for (int d = 1; d < 64; d <<= 1) { s += __shfl_xor(s, d); q += __shfl_xor(q, d); }
  float mu = s * (1.0f / EBD);
  float var = q * (1.0f / EBD) - mu * mu;
  float rs = rsqrtf(var + 1e-5f);
  const float4* g4 = (const float4*)gw;
  const float4* b4 = (const float4*)bw;
  float4 ga = g4[l], gb = g4[l + 64], ba = b4[l], bb = b4[l + 64];
  float4 o0, o1;
  o0.x = (a.x - mu) * rs * ga.x + ba.x;
  o0.y = (a.y - mu) * rs * ga.y + ba.y;
  o0.z = (a.z - mu) * rs * ga.z + ba.z;
  o0.w = (a.w - mu) * rs * ga.w + ba.w;
  o1.x = (b.x - mu) * rs * gb.x + bb.x;
  o1.y = (b.y - mu) * rs * gb.y + bb.y;
  o1.z = (b.z - mu) * rs * gb.z + bb.z;
  o1.w = (b.w - mu) * rs * gb.w + bb.w;
  if (outF) {
    float4* q4 = (float4*)(outF + (size_t)row * EBD);
    q4[l] = o0; q4[l + 64] = o1;
  }
  if (outB) {
    union { bf16 h[4]; float2 f; } u0, u1;
    u0.h[0] = (bf16)o0.x; u0.h[1] = (bf16)o0.y; u0.h[2] = (bf16)o0.z; u0.h[3] = (bf16)o0.w;
    u1.h[0] = (bf16)o1.x; u1.h[1] = (bf16)o1.y; u1.h[2] = (bf16)o1.z; u1.h[3] = (bf16)o1.w;
    float2* r2 = (float2*)(outB + (size_t)row * EBD);
    r2[l] = u0.f; r2[l + 64] = u1.f;
  }
}

// ---------------- host-side orchestration ----------------
extern "C" void kernel_launch(void* const* d_in, const int* in_sizes, int n_in,
                              void* d_out, int out_size, void* d_ws, size_t ws_size,
                              hipStream_t stream) {
  const float* x  = (const float*)d_in[0];
  const float* Wq = (const float*)d_in[1];
  const float* Wk = (const float*)d_in[2];
  const float* Wv = (const float*)d_in[3];
  const float* Wo = (const float*)d_in[4];
  const float* g1 = (const float*)d_in[5];
  const float* b1 = (const float*)d_in[6];
  const float* g2 = (const float*)d_in[7];
  const float* b2 = (const float*)d_in[8];
  const float* W1 = (const float*)d_in[9];
  const float* c1 = (const float*)d_in[10];
  const float* W2 = (const float*)d_in[11];
  const float* c2 = (const float*)d_in[12];
  float* out = (float*)d_out;

  char* p = (char*)d_ws;
  auto take = [&](size_t bytes) { char* r = p; p += (bytes + 255) & ~(size_t)255; return r; };
  bf16*  xb   = (bf16*) take((size_t)MTOK * EBD * 2);     //  4 MB
  bf16*  qb   = (bf16*) take((size_t)MTOK * HE * 2);      // 32 MB
  bf16*  kb   = (bf16*) take((size_t)MTOK * HE * 2);      // 32 MB
  bf16*  vb   = (bf16*) take((size_t)MTOK * HE * 2);      // 32 MB
  bf16*  sc   = (bf16*) take((size_t)32 * SEQ * SEQ * 2); // 64 MB
  float* res1 = (float*)take((size_t)MTOK * EBD * 4);     //  8 MB
  float* nF   = (float*)take((size_t)MTOK * EBD * 4);     //  8 MB
  bf16*  nB   = (bf16*) take((size_t)MTOK * EBD * 2);     //  4 MB
  bf16*  hb   = (bf16*) take((size_t)MTOK * FFD * 2);     // 16 MB
  float* res2 = (float*)take((size_t)MTOK * EBD * 4);     //  8 MB
  bf16*  WqT  = (bf16*) take((size_t)HE * EBD * 2);       //  4 MB
  bf16*  WkT  = (bf16*) take((size_t)HE * EBD * 2);
  bf16*  WvT  = (bf16*) take((size_t)HE * EBD * 2);
  bf16*  WoT  = (bf16*) take((size_t)EBD * HE * 2);
  bf16*  W1T  = (bf16*) take((size_t)FFD * EBD * 2);      //  2 MB
  bf16*  W2T  = (bf16*) take((size_t)EBD * FFD * 2);      //  2 MB  (total ~228 MB)
  bf16*  vT   = kb;   // reuse: kb dead after scores GEMM
  bf16*  ao   = qb;   // reuse: qb dead after scores GEMM

  auto gemm = [&](const bf16* A, const bf16* Bt, float* oF, bf16* oB,
                  const float* bias, const float* res,
                  int Mm, int Nn, int Kk, int lda, int ldb, int ldc, int ldr,
                  long long bAb, long long bAh, long long bBb, long long bBh,
                  long long bCb, long long bCh, int batch, float scale, int relu) {
    dim3 g(Nn / 128, Mm / 128, batch);
    gemm_bt<<<g, dim3(256), 0, stream>>>(A, Bt, oF, oB, bias, res,
        lda, ldb, ldc, ldr, Kk, bAb, bAh, bBb, bBh, bCb, bCh, scale, relu);
  };

  // --- preprocessing: bf16 casts + weight transposes ---
  cast_x_bf16<<<dim3((MTOK * EBD / 4 + 255) / 256), dim3(256), 0, stream>>>(x, xb, MTOK * EBD / 4);
  transpose_cast_w<<<dim3(HE / 32, EBD / 32), dim3(32, 8), 0, stream>>>(Wq, WqT, EBD, HE);
  transpose_cast_w<<<dim3(HE / 32, EBD / 32), dim3(32, 8), 0, stream>>>(Wk, WkT, EBD, HE);
  transpose_cast_w<<<dim3(HE / 32, EBD / 32), dim3(32, 8), 0, stream>>>(Wv, WvT, EBD, HE);
  transpose_cast_w<<<dim3(EBD / 32, HE / 32), dim3(32, 8), 0, stream>>>(Wo, WoT, HE, EBD);
  transpose_cast_w<<<dim3(FFD / 32, EBD / 32), dim3(32, 8), 0, stream>>>(W1, W1T, EBD, FFD);
  transpose_cast_w<<<dim3(EBD / 32, FFD / 32), dim3(32, 8), 0, stream>>>(W2, W2T, FFD, EBD);

  // --- QKV projections (1/sqrt(E) folded into q) ---
  const float qs = 0.04419417382415922f;  // 1/sqrt(512)
  gemm(xb, WqT, nullptr, qb, nullptr, nullptr, MTOK, HE, EBD, EBD, EBD, HE, 0,
       0, 0, 0, 0, 0, 0, 1, qs, 0);
  gemm(xb, WkT, nullptr, kb, nullptr, nullptr, MTOK, HE, EBD, EBD, EBD, HE, 0,
       0, 0, 0, 0, 0, 0, 1, 1.0f, 0);
  gemm(xb, WvT, nullptr, vb, nullptr, nullptr, MTOK, HE, EBD, EBD, EBD, HE, 0,
       0, 0, 0, 0, 0, 0, 1, 1.0f, 0);

  // --- scores = q @ k^T, batched over 32 (b,h) pairs ---
  gemm(qb, kb, nullptr, sc, nullptr, nullptr, SEQ, SEQ, EBD, HE, HE, SEQ, 0,
       (long long)SEQ * HE, EBD, (long long)SEQ * HE, EBD,
       (long long)8 * SEQ * SEQ, (long long)SEQ * SEQ, 32, 1.0f, 0);

  softmax_rows<<<dim3(32 * SEQ / 4), dim3(256), 0, stream>>>(sc);
  transpose_v<<<dim3(EBD / 32, SEQ / 32, 32), dim3(32, 8), 0, stream>>>(vb, vT);

  // --- attn @ v, batched; writes [b][s][h*E] strided ---
  gemm(sc, vT, nullptr, ao, nullptr, nullptr, SEQ, EBD, SEQ, SEQ, SEQ, HE, 0,
       (long long)8 * SEQ * SEQ, (long long)SEQ * SEQ,
       (long long)8 * EBD * SEQ, (long long)EBD * SEQ,
       (long long)SEQ * HE, (long long)EBD, 32, 1.0f, 0);

  // --- out @ Wo + x -> res1 (fp32) ---
  gemm(ao, WoT, res1, nullptr, nullptr, x, MTOK, EBD, HE, HE, HE, EBD, EBD,
       0, 0, 0, 0, 0, 0, 1, 1.0f, 0);
  layernorm_rows<<<dim3(MTOK / 4), dim3(256), 0, stream>>>(res1, g1, b1, nF, nB);

  // --- FF: h = relu(normed @ W1 + c1); ff = h @ W2 + c2 + normed ---
  gemm(nB, W1T, nullptr, hb, c1, nullptr, MTOK, FFD, EBD, EBD, EBD, FFD, 0,
       0, 0, 0, 0, 0, 0, 1, 1.0f, 1);
  gemm(hb, W2T, res2, nullptr, c2, nF, MTOK, EBD, FFD, FFD, FFD, EBD, EBD,
       0, 0, 0, 0, 0, 0, 1, 1.0f, 0);
  layernorm_rows<<<dim3(MTOK / 4), dim3(256), 0, stream>>>(res2, g2, b2, out, nullptr);
}

// Round 2
// 500.884 us; speedup vs baseline: 1.1797x; 1.1797x over previous
//
#include <hip/hip_runtime.h>

// ---------------- constants for this problem ----------------
#define EBD   512      // embed size (= head dim here)
#define NHEAD 8
#define BSZ   4
#define SEQ   1024
#define MTOK  4096     // B*S tokens
#define HE    4096     // H*E
#define FFD   2048     // 4*E

typedef __bf16 bf16;
typedef __attribute__((ext_vector_type(8))) __bf16 bf16x8;
typedef __attribute__((ext_vector_type(4))) float  f32x4;

// async global->LDS, 16B per lane; LDS dest must be wave-uniform base + lane*16
__device__ __forceinline__ void async_load16(const void* g, void* l) {
  __builtin_amdgcn_global_load_lds(
      (const __attribute__((address_space(1))) void*)g,
      (__attribute__((address_space(3))) void*)l, 16, 0, 0);
}

// ---------------- GEMM: C = A @ Bt^T  (A: MxK row-major, Bt: NxK row-major) ----------------
// 128x128 tile, BK=32, 256 threads (4 waves, each 64x64 via 4x4 of 16x16x32 MFMA).
// Generalized batch/split-K via blockIdx.z: zb = z/zdiv, zh = z%zdiv;
// per-operand offsets = zb*bXb + zh*bXh (element strides). Split-K uses zdiv>z so
// zh=z indexes the K-chunk (bAh/bBh = k-offset, bCh = partial-buffer stride).
// Epilogue: v = acc*scale + bias[col] + res[row*ldr+col]; optional relu; f32/bf16 stores.
__global__ void gemm_bt(const bf16* __restrict__ A, const bf16* __restrict__ Bt,
                        float* __restrict__ outF, bf16* __restrict__ outB,
                        const float* __restrict__ bias, const float* __restrict__ res,
                        int lda, int ldb, int ldc, int ldr, int K,
                        long long bAb, long long bAh, long long bBb, long long bBh,
                        long long bCb, long long bCh, int zdiv,
                        float scale, int relu)
{
  __shared__ __attribute__((aligned(16))) bf16 As[128 * 32];
  __shared__ __attribute__((aligned(16))) bf16 Bs[128 * 32];

  const int t = threadIdx.x;
  const int w = t >> 6, l = t & 63;
  const int m0 = blockIdx.y * 128, n0 = blockIdx.x * 128;
  const int z = blockIdx.z;
  const int zb = z / zdiv, zh = z - zb * zdiv;

  const bf16* Ab = A + (size_t)zb * bAb + (size_t)zh * bAh;
  const bf16* Bb = Bt + (size_t)zb * bBb + (size_t)zh * bBh;

  // staging map: thread t handles 16B chunks t and t+256 of each 128x32 tile
  const int srow = t >> 2;            // rows 0..63 (+64 for second chunk)
  const int skc  = (t & 3) * 8;       // k element offset (8 bf16 = 16B)
  const bf16* pA = Ab + (size_t)(m0 + srow) * lda + skc;
  const bf16* pB = Bb + (size_t)(n0 + srow) * ldb + skc;
  const size_t ldA64 = (size_t)64 * lda;
  const size_t ldB64 = (size_t)64 * ldb;

  bf16* ldsA0 = As + w * 512;          // wave-uniform bases (lane*16B added by HW)
  bf16* ldsA1 = As + 2048 + w * 512;
  bf16* ldsB0 = Bs + w * 512;
  bf16* ldsB1 = Bs + 2048 + w * 512;

  const int wm = (w >> 1) * 64, wn = (w & 1) * 64;
  const int lr = l & 15;               // A-row / B-col within 16
  const int lk = (l >> 4) * 8;         // k chunk within 32

  f32x4 acc[4][4];
#pragma unroll
  for (int i = 0; i < 4; ++i)
#pragma unroll
    for (int j = 0; j < 4; ++j) { f32x4 zv = {0.f, 0.f, 0.f, 0.f}; acc[i][j] = zv; }

  const int nkt = K >> 5;
  for (int kt = 0; kt < nkt; ++kt) {
    __syncthreads();                   // previous iteration's ds_reads done
    async_load16(pA, ldsA0);
    async_load16(pA + ldA64, ldsA1);
    async_load16(pB, ldsB0);
    async_load16(pB + ldB64, ldsB1);
    pA += 32; pB += 32;
    __syncthreads();                   // staging complete (vmcnt drained)
    bf16x8 af[4], bv[4];
#pragma unroll
    for (int i = 0; i < 4; ++i)
      af[i] = *(const bf16x8*)&As[(wm + i * 16 + lr) * 32 + lk];
#pragma unroll
    for (int i = 0; i < 4; ++i)
      bv[i] = *(const bf16x8*)&Bs[(wn + i * 16 + lr) * 32 + lk];
#pragma unroll
    for (int mi = 0; mi < 4; ++mi)
#pragma unroll
      for (int ni = 0; ni < 4; ++ni)
        acc[mi][ni] = __builtin_amdgcn_mfma_f32_16x16x32_bf16(af[mi], bv[ni], acc[mi][ni], 0, 0, 0);
  }

  // epilogue: C/D layout col=lane&15, row=(lane>>4)*4+r  [measured m89/m91]
  const size_t offC = (size_t)zb * bCb + (size_t)zh * bCh;
  const int rbase = m0 + wm + (l >> 4) * 4;
#pragma unroll
  for (int ni = 0; ni < 4; ++ni) {
    const int colg = n0 + wn + ni * 16 + lr;
    const float bvs = bias ? bias[colg] : 0.0f;
#pragma unroll
    for (int mi = 0; mi < 4; ++mi) {
#pragma unroll
      for (int r = 0; r < 4; ++r) {
        const int rowg = rbase + mi * 16 + r;
        float v = acc[mi][ni][r] * scale + bvs;
        if (res)  v += res[(size_t)rowg * ldr + colg];
        if (relu) v = fmaxf(v, 0.0f);
        const size_t idx = offC + (size_t)rowg * ldc + colg;
        if (outF) outF[idx] = v;
        if (outB) outB[idx] = (bf16)v;
      }
    }
  }
}

// ---------------- cast x (fp32 -> bf16), 4 elems/thread ----------------
__global__ void cast_x_bf16(const float* __restrict__ in, bf16* __restrict__ out, int n4) {
  int i = blockIdx.x * 256 + threadIdx.x;
  if (i >= n4) return;
  float4 v = ((const float4*)in)[i];
  union { bf16 h[4]; float2 f; } u;
  u.h[0] = (bf16)v.x; u.h[1] = (bf16)v.y; u.h[2] = (bf16)v.z; u.h[3] = (bf16)v.w;
  ((float2*)out)[i] = u.f;
}

// ---------------- weight transpose+cast: in fp32 [K][N] -> out bf16 [N][K] ----------------
__global__ void transpose_cast_w(const float* __restrict__ in, bf16* __restrict__ out,
                                 int K, int N) {
  __shared__ float tile[32][33];
  int n0 = blockIdx.x * 32, k0 = blockIdx.y * 32;
  int tx = threadIdx.x, ty = threadIdx.y;
#pragma unroll
  for (int i = 0; i < 32; i += 8)
    tile[ty + i][tx] = in[(size_t)(k0 + ty + i) * N + n0 + tx];
  __syncthreads();
#pragma unroll
  for (int i = 0; i < 32; i += 8)
    out[(size_t)(n0 + ty + i) * K + k0 + tx] = (bf16)tile[tx][ty + i];
}

// ---------------- V transpose: v[b][s][h][e] (row stride ldv) -> vT[(b,h)][e][s] ----------------
__global__ void transpose_v(const bf16* __restrict__ v, bf16* __restrict__ vT, int ldv) {
  int z = blockIdx.z, b = z >> 3, h = z & 7;
  const bf16* in = v + (size_t)b * SEQ * ldv + (size_t)h * EBD;
  bf16* out = vT + (size_t)z * EBD * SEQ;
  __shared__ bf16 tile[32][33];
  int e0 = blockIdx.x * 32, s0 = blockIdx.y * 32;
  int tx = threadIdx.x, ty = threadIdx.y;
#pragma unroll
  for (int i = 0; i < 32; i += 8)
    tile[ty + i][tx] = in[(size_t)(s0 + ty + i) * ldv + e0 + tx];
  __syncthreads();
#pragma unroll
  for (int i = 0; i < 32; i += 8)
    out[(size_t)(e0 + ty + i) * SEQ + s0 + tx] = tile[tx][ty + i];
}

// ---------------- softmax over rows of 1024 bf16, in-place; one wave per row ----------------
__global__ void softmax_rows(bf16* __restrict__ sc) {
  int l = threadIdx.x & 63, w = threadIdx.x >> 6;
  size_t row = (size_t)blockIdx.x * 4 + w;
  float4* p4 = (float4*)(sc + row * SEQ);
  union U8 { float4 f; bf16 h[8]; };
  U8 u0, u1; u0.f = p4[l]; u1.f = p4[l + 64];
  float v[16];
  float mx = -1e30f;
#pragma unroll
  for (int i = 0; i < 8; ++i) { v[i] = (float)u0.h[i]; mx = fmaxf(mx, v[i]); }
#pragma unroll
  for (int i = 0; i < 8; ++i) { v[8 + i] = (float)u1.h[i]; mx = fmaxf(mx, v[8 + i]); }
#pragma unroll
  for (int d = 1; d < 64; d <<= 1) mx = fmaxf(mx, __shfl_xor(mx, d));
  float s = 0.0f;
#pragma unroll
  for (int i = 0; i < 16; ++i) { v[i] = __expf(v[i] - mx); s += v[i]; }
#pragma unroll
  for (int d = 1; d < 64; d <<= 1) s += __shfl_xor(s, d);
  float inv = 1.0f / s;
#pragma unroll
  for (int i = 0; i < 8; ++i) u0.h[i] = (bf16)(v[i] * inv);
#pragma unroll
  for (int i = 0; i < 8; ++i) u1.h[i] = (bf16)(v[8 + i] * inv);
  p4[l] = u0.f; p4[l + 64] = u1.f;
}

// ---------------- split-K reduce + residual + bias + layernorm, one wave per row ----------------
// parts: ns partial sums [ns][MTOK][EBD] fp32 (stride MTOK*EBD). out = LN(sum + res + bias)
__global__ void reduce_ln(const float* __restrict__ parts, int ns,
                          const float* __restrict__ res, const float* __restrict__ bias,
                          const float* __restrict__ gw, const float* __restrict__ bw,
                          float* __restrict__ outF, bf16* __restrict__ outB) {
  int l = threadIdx.x & 63, w = threadIdx.x >> 6;
  int row = blockIdx.x * 4 + w;
  const long long pstr = (long long)MTOK * EBD;
  float4 a = {0.f, 0.f, 0.f, 0.f}, b = {0.f, 0.f, 0.f, 0.f};
  for (int s = 0; s < ns; ++s) {
    const float4* p = (const float4*)(parts + s * pstr + (size_t)row * EBD);
    float4 pa = p[l], pb = p[l + 64];
    a.x += pa.x; a.y += pa.y; a.z += pa.z; a.w += pa.w;
    b.x += pb.x; b.y += pb.y; b.z += pb.z; b.w += pb.w;
  }
  {
    const float4* p = (const float4*)(res + (size_t)row * EBD);
    float4 pa = p[l], pb = p[l + 64];
    a.x += pa.x; a.y += pa.y; a.z += pa.z; a.w += pa.w;
    b.x += pb.x; b.y += pb.y; b.z += pb.z; b.w += pb.w;
  }
  if (bias) {
    const float4* p = (const float4*)bias;
    float4 pa = p[l], pb = p[l + 64];
    a.x += pa.x; a.y += pa.y; a.z += pa.z; a.w += pa.w;
    b.x += pb.x; b.y += pb.y; b.z += pb.z; b.w += pb.w;
  }
  float s = a.x + a.y + a.z + a.w + b.x + b.y + b.z + b.w;
  float q = a.x * a.x + a.y * a.y + a.z * a.z + a.w * a.w
          + b.x * b.x + b.y * b.y + b.z * b.z + b.w * b.w;
#pragma unroll
  for (int d = 1; d < 64; d <<= 1) { s += __shfl_xor(s, d); q += __shfl_xor(q, d); }
  float mu = s * (1.0f / EBD);
  float var = q * (1.0f / EBD) - mu * mu;
  float rs = rsqrtf(var + 1e-5f);
  const float4* g4 = (const float4*)gw;
  const float4* b4 = (const float4*)bw;
  float4 ga = g4[l], gb = g4[l + 64], ba = b4[l], bb = b4[l + 64];
  float4 o0, o1;
  o0.x = (a.x - mu) * rs * ga.x + ba.x;
  o0.y = (a.y - mu) * rs * ga.y + ba.y;
  o0.z = (a.z - mu) * rs * ga.z + ba.z;
  o0.w = (a.w - mu) * rs * ga.w + ba.w;
  o1.x = (b.x - mu) * rs * gb.x + bb.x;
  o1.y = (b.y - mu) * rs * gb.y + bb.y;
  o1.z = (b.z - mu) * rs * gb.z + bb.z;
  o1.w = (b.w - mu) * rs * gb.w + bb.w;
  if (outF) {
    float4* q4 = (float4*)(outF + (size_t)row * EBD);
    q4[l] = o0; q4[l + 64] = o1;
  }
  if (outB) {
    union { bf16 h[4]; float2 f; } u0, u1;
    u0.h[0] = (bf16)o0.x; u0.h[1] = (bf16)o0.y; u0.h[2] = (bf16)o0.z; u0.h[3] = (bf16)o0.w;
    u1.h[0] = (bf16)o1.x; u1.h[1] = (bf16)o1.y; u1.h[2] = (bf16)o1.z; u1.h[3] = (bf16)o1.w;
    float2* r2 = (float2*)(outB + (size_t)row * EBD);
    r2[l] = u0.f; r2[l + 64] = u1.f;
  }
}

// ---------------- host-side orchestration ----------------
extern "C" void kernel_launch(void* const* d_in, const int* in_sizes, int n_in,
                              void* d_out, int out_size, void* d_ws, size_t ws_size,
                              hipStream_t stream) {
  const float* x  = (const float*)d_in[0];
  const float* Wq = (const float*)d_in[1];
  const float* Wk = (const float*)d_in[2];
  const float* Wv = (const float*)d_in[3];
  const float* Wo = (const float*)d_in[4];
  const float* g1 = (const float*)d_in[5];
  const float* b1 = (const float*)d_in[6];
  const float* g2 = (const float*)d_in[7];
  const float* b2 = (const float*)d_in[8];
  const float* W1 = (const float*)d_in[9];
  const float* c1 = (const float*)d_in[10];
  const float* W2 = (const float*)d_in[11];
  const float* c2 = (const float*)d_in[12];
  float* out = (float*)d_out;

  char* p = (char*)d_ws;
  auto take = [&](size_t bytes) { char* r = p; p += (bytes + 255) & ~(size_t)255; return r; };
  bf16*  xb    = (bf16*) take((size_t)MTOK * EBD * 2);            //   4 MB
  bf16*  qkv   = (bf16*) take((size_t)MTOK * 3 * HE * 2);         //  96 MB [4096][12288]
  bf16*  sc    = (bf16*) take((size_t)32 * SEQ * SEQ * 2);        //  64 MB (reused as split-K fp32 partials, needs 32 MB)
  bf16*  vT    = (bf16*) take((size_t)32 * EBD * SEQ * 2);        //  32 MB
  float* nF    = (float*)take((size_t)MTOK * EBD * 4);            //   8 MB
  bf16*  nB    = (bf16*) take((size_t)MTOK * EBD * 2);            //   4 MB
  bf16*  hb    = (bf16*) take((size_t)MTOK * FFD * 2);            //  16 MB
  bf16*  WqkvT = (bf16*) take((size_t)3 * HE * EBD * 2);          //  12 MB [12288][512]
  bf16*  WoT   = (bf16*) take((size_t)EBD * HE * 2);              //   4 MB
  bf16*  W1T   = (bf16*) take((size_t)FFD * EBD * 2);             //   2 MB
  bf16*  W2T   = (bf16*) take((size_t)EBD * FFD * 2);             //   2 MB   total ~244 MB
  float* parts = (float*)sc;       // split-K partials overlay (sc dead by then)
  bf16*  ao    = qkv;              // attn output reuses q-region cols [0,4096) of qkv, ld 12288

  auto gemm = [&](const bf16* A, const bf16* Bt, float* oF, bf16* oB,
                  const float* bias, const float* res,
                  int Mm, int Nn, int Kk, int lda, int ldb, int ldc, int ldr,
                  long long bAb, long long bAh, long long bBb, long long bBh,
                  long long bCb, long long bCh, int zdiv, int batch,
                  float scale, int relu) {
    dim3 g(Nn / 128, Mm / 128, batch);
    gemm_bt<<<g, dim3(256), 0, stream>>>(A, Bt, oF, oB, bias, res,
        lda, ldb, ldc, ldr, Kk, bAb, bAh, bBb, bBh, bCb, bCh, zdiv, scale, relu);
  };

  // --- preprocessing: bf16 cast + weight transposes (QKV into one stacked [12288][512]) ---
  cast_x_bf16<<<dim3((MTOK * EBD / 4 + 255) / 256), dim3(256), 0, stream>>>(x, xb, MTOK * EBD / 4);
  transpose_cast_w<<<dim3(HE / 32, EBD / 32), dim3(32, 8), 0, stream>>>(Wq, WqkvT, EBD, HE);
  transpose_cast_w<<<dim3(HE / 32, EBD / 32), dim3(32, 8), 0, stream>>>(Wk, WqkvT + (size_t)HE * EBD, EBD, HE);
  transpose_cast_w<<<dim3(HE / 32, EBD / 32), dim3(32, 8), 0, stream>>>(Wv, WqkvT + (size_t)2 * HE * EBD, EBD, HE);
  transpose_cast_w<<<dim3(EBD / 32, HE / 32), dim3(32, 8), 0, stream>>>(Wo, WoT, HE, EBD);
  transpose_cast_w<<<dim3(FFD / 32, EBD / 32), dim3(32, 8), 0, stream>>>(W1, W1T, EBD, FFD);
  transpose_cast_w<<<dim3(EBD / 32, FFD / 32), dim3(32, 8), 0, stream>>>(W2, W2T, FFD, EBD);

  // --- fused QKV projection: [4096][512] @ [12288][512]^T -> qkv [4096][12288] ---
  gemm(xb, WqkvT, nullptr, qkv, nullptr, nullptr, MTOK, 3 * HE, EBD,
       EBD, EBD, 3 * HE, 0, 0, 0, 0, 0, 0, 0, 64, 1, 1.0f, 0);

  // --- scores = (q @ k^T) * 1/sqrt(E), batched over 32 (b,h); q,k are views into qkv ---
  const float qs = 0.04419417382415922f;  // 1/sqrt(512)
  gemm(qkv, qkv + HE, nullptr, sc, nullptr, nullptr, SEQ, SEQ, EBD,
       3 * HE, 3 * HE, SEQ, 0,
       (long long)SEQ * 3 * HE, EBD, (long long)SEQ * 3 * HE, EBD,
       (long long)8 * SEQ * SEQ, (long long)SEQ * SEQ, 8, 32, qs, 0);

  softmax_rows<<<dim3(32 * SEQ / 4), dim3(256), 0, stream>>>(sc);
  transpose_v<<<dim3(EBD / 32, SEQ / 32, 32), dim3(32, 8), 0, stream>>>(qkv + 2 * HE, vT, 3 * HE);

  // --- attn @ v, batched; writes into qkv q-region (cols 0..4095, ld 12288) ---
  gemm(sc, vT, nullptr, ao, nullptr, nullptr, SEQ, EBD, SEQ,
       SEQ, SEQ, 3 * HE, 0,
       (long long)8 * SEQ * SEQ, (long long)SEQ * SEQ,
       (long long)8 * EBD * SEQ, (long long)EBD * SEQ,
       (long long)SEQ * 3 * HE, (long long)EBD, 8, 32, 1.0f, 0);

  // --- out @ Wo, split-K x4 (K=4096 -> 4x1024) -> fp32 partials; then reduce+x+LN1 ---
  gemm(ao, WoT, parts, nullptr, nullptr, nullptr, MTOK, EBD, 1024,
       3 * HE, HE, EBD, 0,
       0, 1024, 0, 1024, 0, (long long)MTOK * EBD, 64, 4, 1.0f, 0);
  reduce_ln<<<dim3(MTOK / 4), dim3(256), 0, stream>>>(parts, 4, x, nullptr, g1, b1, nF, nB);

  // --- FF1: h = relu(normed @ W1 + c1) ---
  gemm(nB, W1T, nullptr, hb, c1, nullptr, MTOK, FFD, EBD,
       EBD, EBD, FFD, 0, 0, 0, 0, 0, 0, 0, 64, 1, 1.0f, 1);

  // --- FF2: split-K x4 (K=2048 -> 4x512) -> partials; then reduce+c2+nF residual+LN2 ---
  gemm(hb, W2T, parts, nullptr, nullptr, nullptr, MTOK, EBD, 512,
       FFD, FFD, EBD, 0,
       0, 512, 0, 512, 0, (long long)MTOK * EBD, 64, 4, 1.0f, 0);
  reduce_ln<<<dim3(MTOK / 4), dim3(256), 0, stream>>>(parts, 4, nF, c2, g2, b2, out, nullptr);
}

// Round 3
// 423.837 us; speedup vs baseline: 1.3942x; 1.1818x over previous
//
#include <hip/hip_runtime.h>

// ---------------- constants for this problem ----------------
#define EBD   512      // embed size (= head dim here)
#define NHEAD 8
#define BSZ   4
#define SEQ   1024
#define MTOK  4096     // B*S tokens
#define HE    4096     // H*E
#define FFD   2048     // 4*E

typedef __bf16 bf16;
typedef __attribute__((ext_vector_type(8))) __bf16 bf16x8;
typedef __attribute__((ext_vector_type(4))) float  f32x4;

// async global->LDS, 16B per lane; LDS dest must be wave-uniform base + lane*16
__device__ __forceinline__ void async_load16(const void* g, void* l) {
  __builtin_amdgcn_global_load_lds(
      (const __attribute__((address_space(1))) void*)g,
      (__attribute__((address_space(3))) void*)l, 16, 0, 0);
}

// ---------------- GEMM: C = A @ Bt^T  (A: MxK row-major, Bt: NxK row-major) ----------------
// 128x128 tile, BK=32, 256 threads (4 waves, each 64x64 via 4x4 of 16x16x32 MFMA).
// Batch/split-K via blockIdx.z: zb=z/zdiv, zh=z%zdiv; offsets zb*bXb+zh*bXh (elements).
// Epilogue is LDS-staged for coalesced full-sector stores:
//   normal: v = acc*scale + bias[col] + res[row*ldr+col]; opt relu; bf16 (outB) or f32 (outF).
//   vmode (QKV only): col-tiles n0>=8192 are the V projection; staged transposed and
//   written directly as vT[(b*8+h)][e][s] (eliminates the separate transpose_v kernel).
__global__ void gemm_bt(const bf16* __restrict__ A, const bf16* __restrict__ Bt,
                        float* __restrict__ outF, bf16* __restrict__ outB,
                        bf16* __restrict__ vTout,
                        const float* __restrict__ bias, const float* __restrict__ res,
                        int lda, int ldb, int ldc, int ldr, int K,
                        long long bAb, long long bAh, long long bBb, long long bBh,
                        long long bCb, long long bCh, int zdiv,
                        float scale, int relu, int vmode)
{
  __shared__ __attribute__((aligned(16))) bf16 As[128 * 32];
  __shared__ __attribute__((aligned(16))) bf16 Bs[128 * 32];
  __shared__ __attribute__((aligned(16))) float Cs[4][64 * 36];  // 9216B per wave

  const int t = threadIdx.x;
  const int w = t >> 6, l = t & 63;
  const int m0 = blockIdx.y * 128, n0 = blockIdx.x * 128;
  const int z = blockIdx.z;
  const int zb = z / zdiv, zh = z - zb * zdiv;

  const bf16* Ab = A + (size_t)zb * bAb + (size_t)zh * bAh;
  const bf16* Bb = Bt + (size_t)zb * bBb + (size_t)zh * bBh;

  // staging map: thread t handles 16B chunks t and t+256 of each 128x32 tile
  const int srow = t >> 2;            // rows 0..63 (+64 for second chunk)
  const int skc  = (t & 3) * 8;       // k element offset (8 bf16 = 16B)
  const bf16* pA = Ab + (size_t)(m0 + srow) * lda + skc;
  const bf16* pB = Bb + (size_t)(n0 + srow) * ldb + skc;
  const size_t ldA64 = (size_t)64 * lda;
  const size_t ldB64 = (size_t)64 * ldb;

  bf16* ldsA0 = As + w * 512;          // wave-uniform bases (lane*16B added by HW)
  bf16* ldsA1 = As + 2048 + w * 512;
  bf16* ldsB0 = Bs + w * 512;
  bf16* ldsB1 = Bs + 2048 + w * 512;

  const int wm = (w >> 1) * 64, wn = (w & 1) * 64;
  const int lr = l & 15;               // A-row / B-col within 16
  const int lk = (l >> 4) * 8;         // k chunk within 32

  f32x4 acc[4][4];
#pragma unroll
  for (int i = 0; i < 4; ++i)
#pragma unroll
    for (int j = 0; j < 4; ++j) { f32x4 zv = {0.f, 0.f, 0.f, 0.f}; acc[i][j] = zv; }

  const int nkt = K >> 5;
  for (int kt = 0; kt < nkt; ++kt) {
    __syncthreads();                   // previous iteration's ds_reads done
    async_load16(pA, ldsA0);
    async_load16(pA + ldA64, ldsA1);
    async_load16(pB, ldsB0);
    async_load16(pB + ldB64, ldsB1);
    pA += 32; pB += 32;
    __syncthreads();                   // staging complete (vmcnt drained)
    bf16x8 af[4], bv[4];
#pragma unroll
    for (int i = 0; i < 4; ++i)
      af[i] = *(const bf16x8*)&As[(wm + i * 16 + lr) * 32 + lk];
#pragma unroll
    for (int i = 0; i < 4; ++i)
      bv[i] = *(const bf16x8*)&Bs[(wn + i * 16 + lr) * 32 + lk];
#pragma unroll
    for (int mi = 0; mi < 4; ++mi)
#pragma unroll
      for (int ni = 0; ni < 4; ++ni)
        acc[mi][ni] = __builtin_amdgcn_mfma_f32_16x16x32_bf16(af[mi], bv[ni], acc[mi][ni], 0, 0, 0);
  }

  // ---- LDS-staged epilogue (C/D layout: col=lane&15, row=(lane>>4)*4+r) ----
  float* cs = Cs[w];
  const size_t offC = (size_t)zb * bCb + (size_t)zh * bCh;
  const int rq = (l >> 4) * 4;         // reg-group row base

  if (vmode && n0 >= 8192) {
    // ---- V-projection tiles: store transposed into vT[(b*8+h)][e][s] ----
    const int b  = (m0 + wm) >> 10;
    const int s0 = (m0 + wm) & 1023;
#pragma unroll
    for (int p = 0; p < 2; ++p) {
      __syncthreads();
#pragma unroll
      for (int ni2 = 0; ni2 < 2; ++ni2) {
        const int ni = 2 * p + ni2;
        const int cl = ni2 * 16 + lr;
#pragma unroll
        for (int mi = 0; mi < 4; ++mi)
#pragma unroll
          for (int r = 0; r < 4; ++r)
            cs[cl * 68 + mi * 16 + rq + r] = acc[mi][ni][r];  // transposed: [col][row]
      }
      __syncthreads();
      const int c = l & 31, half = l >> 5;
      int e = (n0 - 8192) + wn + p * 32 + c;
      const int h = e >> 9; e &= 511;
      bf16* dst = vTout + (((size_t)(b * 8 + h) * 512 + e) << 10) + s0 + half * 32;
      float vv[32];
#pragma unroll
      for (int j = 0; j < 8; ++j)
        *(f32x4*)&vv[4 * j] = *(const f32x4*)&cs[c * 68 + half * 32 + 4 * j];
#pragma unroll
      for (int q4 = 0; q4 < 4; ++q4) {
        union { bf16 h8[8]; float4 f; } u;
#pragma unroll
        for (int j = 0; j < 8; ++j) u.h8[j] = (bf16)vv[q4 * 8 + j];
        *(float4*)(dst + q4 * 8) = u.f;
      }
    }
    return;
  }

#pragma unroll
  for (int p = 0; p < 2; ++p) {
    __syncthreads();
#pragma unroll
    for (int ni2 = 0; ni2 < 2; ++ni2) {
      const int ni = 2 * p + ni2;
      const int cl = ni2 * 16 + lr;
#pragma unroll
      for (int mi = 0; mi < 4; ++mi)
#pragma unroll
        for (int r = 0; r < 4; ++r)
          cs[(mi * 16 + rq + r) * 36 + cl] = acc[mi][ni][r];
    }
    __syncthreads();
    if (outB) {
      // bf16 output: lane packs 8 consecutive cols of one row -> 16B store
      const int rl0 = l >> 2, c8 = (l & 3) * 8;
#pragma unroll
      for (int sub = 0; sub < 4; ++sub) {
        const int rl = sub * 16 + rl0;
        const int rowg = m0 + wm + rl;
        const int colg = n0 + wn + p * 32 + c8;
        float vv[8];
        *(f32x4*)&vv[0] = *(const f32x4*)&cs[rl * 36 + c8];
        *(f32x4*)&vv[4] = *(const f32x4*)&cs[rl * 36 + c8 + 4];
#pragma unroll
        for (int j = 0; j < 8; ++j) vv[j] *= scale;
        if (bias) {
          const float4 b0 = *(const float4*)(bias + colg);
          const float4 b1 = *(const float4*)(bias + colg + 4);
          vv[0] += b0.x; vv[1] += b0.y; vv[2] += b0.z; vv[3] += b0.w;
          vv[4] += b1.x; vv[5] += b1.y; vv[6] += b1.z; vv[7] += b1.w;
        }
        if (res) {
          const float4 r0 = *(const float4*)(res + (size_t)rowg * ldr + colg);
          const float4 r1 = *(const float4*)(res + (size_t)rowg * ldr + colg + 4);
          vv[0] += r0.x; vv[1] += r0.y; vv[2] += r0.z; vv[3] += r0.w;
          vv[4] += r1.x; vv[5] += r1.y; vv[6] += r1.z; vv[7] += r1.w;
        }
        if (relu)
#pragma unroll
          for (int j = 0; j < 8; ++j) vv[j] = fmaxf(vv[j], 0.0f);
        union { bf16 h8[8]; float4 f; } u;
#pragma unroll
        for (int j = 0; j < 8; ++j) u.h8[j] = (bf16)vv[j];
        *(float4*)(outB + offC + (size_t)rowg * ldc + colg) = u.f;
      }
    } else {
      // f32 output (split-K partials): lane stores float4
      const int rl0 = l >> 3, c4 = (l & 7) * 4;
#pragma unroll
      for (int sub = 0; sub < 8; ++sub) {
        const int rl = sub * 8 + rl0;
        const int rowg = m0 + wm + rl;
        const int colg = n0 + wn + p * 32 + c4;
        float4 v = *(const float4*)&cs[rl * 36 + c4];
        v.x *= scale; v.y *= scale; v.z *= scale; v.w *= scale;
        if (bias) {
          const float4 b0 = *(const float4*)(bias + colg);
          v.x += b0.x; v.y += b0.y; v.z += b0.z; v.w += b0.w;
        }
        if (res) {
          const float4 r0 = *(const float4*)(res + (size_t)rowg * ldr + colg);
          v.x += r0.x; v.y += r0.y; v.z += r0.z; v.w += r0.w;
        }
        if (relu) {
          v.x = fmaxf(v.x, 0.f); v.y = fmaxf(v.y, 0.f);
          v.z = fmaxf(v.z, 0.f); v.w = fmaxf(v.w, 0.f);
        }
        *(float4*)(outF + offC + (size_t)rowg * ldc + colg) = v;
      }
    }
  }
}

// ---------------- cast x (fp32 -> bf16), 4 elems/thread ----------------
__global__ void cast_x_bf16(const float* __restrict__ in, bf16* __restrict__ out, int n4) {
  int i = blockIdx.x * 256 + threadIdx.x;
  if (i >= n4) return;
  float4 v = ((const float4*)in)[i];
  union { bf16 h[4]; float2 f; } u;
  u.h[0] = (bf16)v.x; u.h[1] = (bf16)v.y; u.h[2] = (bf16)v.z; u.h[3] = (bf16)v.w;
  ((float2*)out)[i] = u.f;
}

// ---------------- weight transpose+cast: in fp32 [K][N] -> out bf16 [N][K] ----------------
__global__ void transpose_cast_w(const float* __restrict__ in, bf16* __restrict__ out,
                                 int K, int N) {
  __shared__ float tile[32][33];
  int n0 = blockIdx.x * 32, k0 = blockIdx.y * 32;
  int tx = threadIdx.x, ty = threadIdx.y;
#pragma unroll
  for (int i = 0; i < 32; i += 8)
    tile[ty + i][tx] = in[(size_t)(k0 + ty + i) * N + n0 + tx];
  __syncthreads();
#pragma unroll
  for (int i = 0; i < 32; i += 8)
    out[(size_t)(n0 + ty + i) * K + k0 + tx] = (bf16)tile[tx][ty + i];
}

// ---------------- softmax over rows of 1024 bf16, in-place; one wave per row ----------------
__global__ void softmax_rows(bf16* __restrict__ sc) {
  int l = threadIdx.x & 63, w = threadIdx.x >> 6;
  size_t row = (size_t)blockIdx.x * 4 + w;
  float4* p4 = (float4*)(sc + row * SEQ);
  union U8 { float4 f; bf16 h[8]; };
  U8 u0, u1; u0.f = p4[l]; u1.f = p4[l + 64];
  float v[16];
  float mx = -1e30f;
#pragma unroll
  for (int i = 0; i < 8; ++i) { v[i] = (float)u0.h[i]; mx = fmaxf(mx, v[i]); }
#pragma unroll
  for (int i = 0; i < 8; ++i) { v[8 + i] = (float)u1.h[i]; mx = fmaxf(mx, v[8 + i]); }
#pragma unroll
  for (int d = 1; d < 64; d <<= 1) mx = fmaxf(mx, __shfl_xor(mx, d));
  float s = 0.0f;
#pragma unroll
  for (int i = 0; i < 16; ++i) { v[i] = __expf(v[i] - mx); s += v[i]; }
#pragma unroll
  for (int d = 1; d < 64; d <<= 1) s += __shfl_xor(s, d);
  float inv = 1.0f / s;
#pragma unroll
  for (int i = 0; i < 8; ++i) u0.h[i] = (bf16)(v[i] * inv);
#pragma unroll
  for (int i = 0; i < 8; ++i) u1.h[i] = (bf16)(v[8 + i] * inv);
  p4[l] = u0.f; p4[l + 64] = u1.f;
}

// ---------------- split-K reduce + residual + bias + layernorm, one wave per row ----------------
__global__ void reduce_ln(const float* __restrict__ parts, int ns,
                          const float* __restrict__ res, const float* __restrict__ bias,
                          const float* __restrict__ gw, const float* __restrict__ bw,
                          float* __restrict__ outF, bf16* __restrict__ outB) {
  int l = threadIdx.x & 63, w = threadIdx.x >> 6;
  int row = blockIdx.x * 4 + w;
  const long long pstr = (long long)MTOK * EBD;
  float4 a = {0.f, 0.f, 0.f, 0.f}, b = {0.f, 0.f, 0.f, 0.f};
  for (int s = 0; s < ns; ++s) {
    const float4* p = (const float4*)(parts + s * pstr + (size_t)row * EBD);
    float4 pa = p[l], pb = p[l + 64];
    a.x += pa.x; a.y += pa.y; a.z += pa.z; a.w += pa.w;
    b.x += pb.x; b.y += pb.y; b.z += pb.z; b.w += pb.w;
  }
  {
    const float4* p = (const float4*)(res + (size_t)row * EBD);
    float4 pa = p[l], pb = p[l + 64];
    a.x += pa.x; a.y += pa.y; a.z += pa.z; a.w += pa.w;
    b.x += pb.x; b.y += pb.y; b.z += pb.z; b.w += pb.w;
  }
  if (bias) {
    const float4* p = (const float4*)bias;
    float4 pa = p[l], pb = p[l + 64];
    a.x += pa.x; a.y += pa.y; a.z += pa.z; a.w += pa.w;
    b.x += pb.x; b.y += pb.y; b.z += pb.z; b.w += pb.w;
  }
  float s = a.x + a.y + a.z + a.w + b.x + b.y + b.z + b.w;
  float q = a.x * a.x + a.y * a.y + a.z * a.z + a.w * a.w
          + b.x * b.x + b.y * b.y + b.z * b.z + b.w * b.w;
#pragma unroll
  for (int d = 1; d < 64; d <<= 1) { s += __shfl_xor(s, d); q += __shfl_xor(q, d); }
  float mu = s * (1.0f / EBD);
  float var = q * (1.0f / EBD) - mu * mu;
  float rs = rsqrtf(var + 1e-5f);
  const float4* g4 = (const float4*)gw;
  const float4* b4 = (const float4*)bw;
  float4 ga = g4[l], gb = g4[l + 64], ba = b4[l], bb = b4[l + 64];
  float4 o0, o1;
  o0.x = (a.x - mu) * rs * ga.x + ba.x;
  o0.y = (a.y - mu) * rs * ga.y + ba.y;
  o0.z = (a.z - mu) * rs * ga.z + ba.z;
  o0.w = (a.w - mu) * rs * ga.w + ba.w;
  o1.x = (b.x - mu) * rs * gb.x + bb.x;
  o1.y = (b.y - mu) * rs * gb.y + bb.y;
  o1.z = (b.z - mu) * rs * gb.z + bb.z;
  o1.w = (b.w - mu) * rs * gb.w + bb.w;
  if (outF) {
    float4* q4 = (float4*)(outF + (size_t)row * EBD);
    q4[l] = o0; q4[l + 64] = o1;
  }
  if (outB) {
    union { bf16 h[4]; float2 f; } u0, u1;
    u0.h[0] = (bf16)o0.x; u0.h[1] = (bf16)o0.y; u0.h[2] = (bf16)o0.z; u0.h[3] = (bf16)o0.w;
    u1.h[0] = (bf16)o1.x; u1.h[1] = (bf16)o1.y; u1.h[2] = (bf16)o1.z; u1.h[3] = (bf16)o1.w;
    float2* r2 = (float2*)(outB + (size_t)row * EBD);
    r2[l] = u0.f; r2[l + 64] = u1.f;
  }
}

// ---------------- host-side orchestration ----------------
extern "C" void kernel_launch(void* const* d_in, const int* in_sizes, int n_in,
                              void* d_out, int out_size, void* d_ws, size_t ws_size,
                              hipStream_t stream) {
  const float* x  = (const float*)d_in[0];
  const float* Wq = (const float*)d_in[1];
  const float* Wk = (const float*)d_in[2];
  const float* Wv = (const float*)d_in[3];
  const float* Wo = (const float*)d_in[4];
  const float* g1 = (const float*)d_in[5];
  const float* b1 = (const float*)d_in[6];
  const float* g2 = (const float*)d_in[7];
  const float* b2 = (const float*)d_in[8];
  const float* W1 = (const float*)d_in[9];
  const float* c1 = (const float*)d_in[10];
  const float* W2 = (const float*)d_in[11];
  const float* c2 = (const float*)d_in[12];
  float* out = (float*)d_out;

  char* p = (char*)d_ws;
  auto take = [&](size_t bytes) { char* r = p; p += (bytes + 255) & ~(size_t)255; return r; };
  bf16*  xb    = (bf16*) take((size_t)MTOK * EBD * 2);            //   4 MB
  bf16*  qk    = (bf16*) take((size_t)MTOK * 2 * HE * 2);         //  64 MB [4096][8192]
  bf16*  vT    = (bf16*) take((size_t)32 * EBD * SEQ * 2);        //  32 MB [(b,h)][e][s]
  bf16*  sc    = (bf16*) take((size_t)32 * SEQ * SEQ * 2);        //  64 MB (split-K fp32 partials overlay)
  bf16*  ao    = (bf16*) take((size_t)MTOK * HE * 2);             //  32 MB
  float* nF    = (float*)take((size_t)MTOK * EBD * 4);            //   8 MB
  bf16*  nB    = (bf16*) take((size_t)MTOK * EBD * 2);            //   4 MB
  bf16*  hb    = (bf16*) take((size_t)MTOK * FFD * 2);            //  16 MB
  bf16*  WqkvT = (bf16*) take((size_t)3 * HE * EBD * 2);          //  12 MB [12288][512]
  bf16*  WoT   = (bf16*) take((size_t)EBD * HE * 2);              //   4 MB
  bf16*  W1T   = (bf16*) take((size_t)FFD * EBD * 2);             //   2 MB
  bf16*  W2T   = (bf16*) take((size_t)EBD * FFD * 2);             //   2 MB   total ~244 MB
  float* parts = (float*)sc;       // split-K partials overlay (sc dead by then)

  auto gemm = [&](const bf16* A, const bf16* Bt, float* oF, bf16* oB, bf16* vTo,
                  const float* bias, const float* res,
                  int Mm, int Nn, int Kk, int lda, int ldb, int ldc, int ldr,
                  long long bAb, long long bAh, long long bBb, long long bBh,
                  long long bCb, long long bCh, int zdiv, int batch,
                  float scale, int relu, int vmode) {
    dim3 g(Nn / 128, Mm / 128, batch);
    gemm_bt<<<g, dim3(256), 0, stream>>>(A, Bt, oF, oB, vTo, bias, res,
        lda, ldb, ldc, ldr, Kk, bAb, bAh, bBb, bBh, bCb, bCh, zdiv, scale, relu, vmode);
  };

  // --- preprocessing: bf16 cast + weight transposes (QKV stacked [12288][512]) ---
  cast_x_bf16<<<dim3((MTOK * EBD / 4 + 255) / 256), dim3(256), 0, stream>>>(x, xb, MTOK * EBD / 4);
  transpose_cast_w<<<dim3(HE / 32, EBD / 32), dim3(32, 8), 0, stream>>>(Wq, WqkvT, EBD, HE);
  transpose_cast_w<<<dim3(HE / 32, EBD / 32), dim3(32, 8), 0, stream>>>(Wk, WqkvT + (size_t)HE * EBD, EBD, HE);
  transpose_cast_w<<<dim3(HE / 32, EBD / 32), dim3(32, 8), 0, stream>>>(Wv, WqkvT + (size_t)2 * HE * EBD, EBD, HE);
  transpose_cast_w<<<dim3(EBD / 32, HE / 32), dim3(32, 8), 0, stream>>>(Wo, WoT, HE, EBD);
  transpose_cast_w<<<dim3(FFD / 32, EBD / 32), dim3(32, 8), 0, stream>>>(W1, W1T, EBD, FFD);
  transpose_cast_w<<<dim3(EBD / 32, FFD / 32), dim3(32, 8), 0, stream>>>(W2, W2T, FFD, EBD);

  // --- fused QKV projection: q,k -> qk [4096][8192]; V -> vT transposed in-epilogue ---
  gemm(xb, WqkvT, nullptr, qk, vT, nullptr, nullptr, MTOK, 3 * HE, EBD,
       EBD, EBD, 2 * HE, 0, 0, 0, 0, 0, 0, 0, 64, 1, 1.0f, 0, 1);

  // --- scores = (q @ k^T) * 1/sqrt(E), batched over 32 (b,h) ---
  const float qs = 0.04419417382415922f;  // 1/sqrt(512)
  gemm(qk, qk + HE, nullptr, sc, nullptr, nullptr, nullptr, SEQ, SEQ, EBD,
       2 * HE, 2 * HE, SEQ, 0,
       (long long)SEQ * 2 * HE, EBD, (long long)SEQ * 2 * HE, EBD,
       (long long)8 * SEQ * SEQ, (long long)SEQ * SEQ, 8, 32, qs, 0, 0);

  softmax_rows<<<dim3(32 * SEQ / 4), dim3(256), 0, stream>>>(sc);

  // --- attn @ v, batched; ao [4096][4096] ---
  gemm(sc, vT, nullptr, ao, nullptr, nullptr, nullptr, SEQ, EBD, SEQ,
       SEQ, SEQ, HE, 0,
       (long long)8 * SEQ * SEQ, (long long)SEQ * SEQ,
       (long long)8 * EBD * SEQ, (long long)EBD * SEQ,
       (long long)SEQ * HE, (long long)EBD, 8, 32, 1.0f, 0, 0);

  // --- out @ Wo, split-K x4 (K=4096 -> 4x1024) -> fp32 partials; reduce + x + LN1 ---
  gemm(ao, WoT, parts, nullptr, nullptr, nullptr, nullptr, MTOK, EBD, 1024,
       HE, HE, EBD, 0,
       0, 1024, 0, 1024, 0, (long long)MTOK * EBD, 64, 4, 1.0f, 0, 0);
  reduce_ln<<<dim3(MTOK / 4), dim3(256), 0, stream>>>(parts, 4, x, nullptr, g1, b1, nF, nB);

  // --- FF1: h = relu(normed @ W1 + c1) ---
  gemm(nB, W1T, nullptr, hb, nullptr, c1, nullptr, MTOK, FFD, EBD,
       EBD, EBD, FFD, 0, 0, 0, 0, 0, 0, 0, 64, 1, 1.0f, 1, 0);

  // --- FF2: split-K x4 (K=2048 -> 4x512) -> partials; reduce + c2 + nF + LN2 ---
  gemm(hb, W2T, parts, nullptr, nullptr, nullptr, nullptr, MTOK, EBD, 512,
       FFD, FFD, EBD, 0,
       0, 512, 0, 512, 0, (long long)MTOK * EBD, 64, 4, 1.0f, 0, 0);
  reduce_ln<<<dim3(MTOK / 4), dim3(256), 0, stream>>>(parts, 4, nF, c2, g2, b2, out, nullptr);
}

// Round 4
// 423.369 us; speedup vs baseline: 1.3957x; 1.0011x over previous
//
#include <hip/hip_runtime.h>

// ---------------- constants for this problem ----------------
#define EBD   512      // embed size (= head dim here)
#define NHEAD 8
#define BSZ   4
#define SEQ   1024
#define MTOK  4096     // B*S tokens
#define HE    4096     // H*E
#define FFD   2048     // 4*E

typedef __bf16 bf16;
typedef __attribute__((ext_vector_type(8))) __bf16 bf16x8;
typedef __attribute__((ext_vector_type(4))) float  f32x4;

// async global->LDS, 16B per lane; LDS dest must be wave-uniform base + lane*16
__device__ __forceinline__ void async_load16(const void* g, void* l) {
  __builtin_amdgcn_global_load_lds(
      (const __attribute__((address_space(1))) void*)g,
      (__attribute__((address_space(3))) void*)l, 16, 0, 0);
}

// ---------------- GEMM: C = A @ Bt^T  (A: MxK row-major, Bt: NxK row-major) ----------------
// 128x128 tile, BK=32, 256 threads (4 waves, each 64x64 via 4x4 of 16x16x32 MFMA).
// Batch/split-K via blockIdx.z: zb=z/zdiv, zh=z%zdiv; offsets zb*bXb+zh*bXh (elements).
// LDS: single 36864B block; As(8K)+Bs(8K) overlaid with the epilogue stage Cs[4][2304].
// Safe because every epilogue pass begins with __syncthreads() which drains the last
// ds_reads of As/Bs before Cs writes land. 36864B -> 4 blocks/CU (was 53248 -> 3).
__global__ void gemm_bt(const bf16* __restrict__ A, const bf16* __restrict__ Bt,
                        float* __restrict__ outF, bf16* __restrict__ outB,
                        bf16* __restrict__ vTout,
                        const float* __restrict__ bias, const float* __restrict__ res,
                        int lda, int ldb, int ldc, int ldr, int K,
                        long long bAb, long long bAh, long long bBb, long long bBh,
                        long long bCb, long long bCh, int zdiv,
                        float scale, int relu, int vmode)
{
  __shared__ __attribute__((aligned(16))) float Smem[4 * 2304];  // 36864 B
  bf16* As = (bf16*)Smem;              // 128*32 bf16 = 8 KB
  bf16* Bs = (bf16*)Smem + 128 * 32;   // next 8 KB

  const int t = threadIdx.x;
  const int w = t >> 6, l = t & 63;
  const int m0 = blockIdx.y * 128, n0 = blockIdx.x * 128;
  const int z = blockIdx.z;
  const int zb = z / zdiv, zh = z - zb * zdiv;

  const bf16* Ab = A + (size_t)zb * bAb + (size_t)zh * bAh;
  const bf16* Bb = Bt + (size_t)zb * bBb + (size_t)zh * bBh;

  // staging map: thread t handles 16B chunks t and t+256 of each 128x32 tile
  const int srow = t >> 2;            // rows 0..63 (+64 for second chunk)
  const int skc  = (t & 3) * 8;       // k element offset (8 bf16 = 16B)
  const bf16* pA = Ab + (size_t)(m0 + srow) * lda + skc;
  const bf16* pB = Bb + (size_t)(n0 + srow) * ldb + skc;
  const size_t ldA64 = (size_t)64 * lda;
  const size_t ldB64 = (size_t)64 * ldb;

  bf16* ldsA0 = As + w * 512;          // wave-uniform bases (lane*16B added by HW)
  bf16* ldsA1 = As + 2048 + w * 512;
  bf16* ldsB0 = Bs + w * 512;
  bf16* ldsB1 = Bs + 2048 + w * 512;

  const int wm = (w >> 1) * 64, wn = (w & 1) * 64;
  const int lr = l & 15;               // A-row / B-col within 16
  const int lk = (l >> 4) * 8;         // k chunk within 32

  f32x4 acc[4][4];
#pragma unroll
  for (int i = 0; i < 4; ++i)
#pragma unroll
    for (int j = 0; j < 4; ++j) { f32x4 zv = {0.f, 0.f, 0.f, 0.f}; acc[i][j] = zv; }

  const int nkt = K >> 5;
  for (int kt = 0; kt < nkt; ++kt) {
    __syncthreads();                   // previous iteration's ds_reads done
    async_load16(pA, ldsA0);
    async_load16(pA + ldA64, ldsA1);
    async_load16(pB, ldsB0);
    async_load16(pB + ldB64, ldsB1);
    pA += 32; pB += 32;
    __syncthreads();                   // staging complete (vmcnt drained)
    bf16x8 af[4], bv[4];
#pragma unroll
    for (int i = 0; i < 4; ++i)
      af[i] = *(const bf16x8*)&As[(wm + i * 16 + lr) * 32 + lk];
#pragma unroll
    for (int i = 0; i < 4; ++i)
      bv[i] = *(const bf16x8*)&Bs[(wn + i * 16 + lr) * 32 + lk];
#pragma unroll
    for (int mi = 0; mi < 4; ++mi)
#pragma unroll
      for (int ni = 0; ni < 4; ++ni)
        acc[mi][ni] = __builtin_amdgcn_mfma_f32_16x16x32_bf16(af[mi], bv[ni], acc[mi][ni], 0, 0, 0);
  }

  // ---- LDS-staged epilogue (C/D layout: col=lane&15, row=(lane>>4)*4+r) ----
  float* cs = Smem + w * 2304;         // 64x36 fp32 per wave (overlays As/Bs)
  const size_t offC = (size_t)zb * bCb + (size_t)zh * bCh;
  const int rq = (l >> 4) * 4;         // reg-group row base

  if (vmode && n0 >= 8192) {
    // ---- V-projection tiles: store transposed into vT[(b*8+h)][e][s] ----
    const int b  = (m0 + wm) >> 10;
    const int s0 = (m0 + wm) & 1023;
#pragma unroll
    for (int p = 0; p < 2; ++p) {
      __syncthreads();
#pragma unroll
      for (int ni2 = 0; ni2 < 2; ++ni2) {
        const int ni = 2 * p + ni2;
        const int cl = ni2 * 16 + lr;
#pragma unroll
        for (int mi = 0; mi < 4; ++mi)
#pragma unroll
          for (int r = 0; r < 4; ++r)
            cs[cl * 68 + mi * 16 + rq + r] = acc[mi][ni][r];  // transposed: [col][row]
      }
      __syncthreads();
      const int c = l & 31, half = l >> 5;
      int e = (n0 - 8192) + wn + p * 32 + c;
      const int h = e >> 9; e &= 511;
      bf16* dst = vTout + (((size_t)(b * 8 + h) * 512 + e) << 10) + s0 + half * 32;
      float vv[32];
#pragma unroll
      for (int j = 0; j < 8; ++j)
        *(f32x4*)&vv[4 * j] = *(const f32x4*)&cs[c * 68 + half * 32 + 4 * j];
#pragma unroll
      for (int q4 = 0; q4 < 4; ++q4) {
        union { bf16 h8[8]; float4 f; } u;
#pragma unroll
        for (int j = 0; j < 8; ++j) u.h8[j] = (bf16)vv[q4 * 8 + j];
        *(float4*)(dst + q4 * 8) = u.f;
      }
    }
    return;
  }

#pragma unroll
  for (int p = 0; p < 2; ++p) {
    __syncthreads();
#pragma unroll
    for (int ni2 = 0; ni2 < 2; ++ni2) {
      const int ni = 2 * p + ni2;
      const int cl = ni2 * 16 + lr;
#pragma unroll
      for (int mi = 0; mi < 4; ++mi)
#pragma unroll
        for (int r = 0; r < 4; ++r)
          cs[(mi * 16 + rq + r) * 36 + cl] = acc[mi][ni][r];
    }
    __syncthreads();
    if (outB) {
      // bf16 output: lane packs 8 consecutive cols of one row -> 16B store
      const int rl0 = l >> 2, c8 = (l & 3) * 8;
#pragma unroll
      for (int sub = 0; sub < 4; ++sub) {
        const int rl = sub * 16 + rl0;
        const int rowg = m0 + wm + rl;
        const int colg = n0 + wn + p * 32 + c8;
        float vv[8];
        *(f32x4*)&vv[0] = *(const f32x4*)&cs[rl * 36 + c8];
        *(f32x4*)&vv[4] = *(const f32x4*)&cs[rl * 36 + c8 + 4];
#pragma unroll
        for (int j = 0; j < 8; ++j) vv[j] *= scale;
        if (bias) {
          const float4 b0 = *(const float4*)(bias + colg);
          const float4 b1 = *(const float4*)(bias + colg + 4);
          vv[0] += b0.x; vv[1] += b0.y; vv[2] += b0.z; vv[3] += b0.w;
          vv[4] += b1.x; vv[5] += b1.y; vv[6] += b1.z; vv[7] += b1.w;
        }
        if (res) {
          const float4 r0 = *(const float4*)(res + (size_t)rowg * ldr + colg);
          const float4 r1 = *(const float4*)(res + (size_t)rowg * ldr + colg + 4);
          vv[0] += r0.x; vv[1] += r0.y; vv[2] += r0.z; vv[3] += r0.w;
          vv[4] += r1.x; vv[5] += r1.y; vv[6] += r1.z; vv[7] += r1.w;
        }
        if (relu)
#pragma unroll
          for (int j = 0; j < 8; ++j) vv[j] = fmaxf(vv[j], 0.0f);
        union { bf16 h8[8]; float4 f; } u;
#pragma unroll
        for (int j = 0; j < 8; ++j) u.h8[j] = (bf16)vv[j];
        *(float4*)(outB + offC + (size_t)rowg * ldc + colg) = u.f;
      }
    } else {
      // f32 output (split-K partials): lane stores float4
      const int rl0 = l >> 3, c4 = (l & 7) * 4;
#pragma unroll
      for (int sub = 0; sub < 8; ++sub) {
        const int rl = sub * 8 + rl0;
        const int rowg = m0 + wm + rl;
        const int colg = n0 + wn + p * 32 + c4;
        float4 v = *(const float4*)&cs[rl * 36 + c4];
        v.x *= scale; v.y *= scale; v.z *= scale; v.w *= scale;
        if (bias) {
          const float4 b0 = *(const float4*)(bias + colg);
          v.x += b0.x; v.y += b0.y; v.z += b0.z; v.w += b0.w;
        }
        if (res) {
          const float4 r0 = *(const float4*)(res + (size_t)rowg * ldr + colg);
          v.x += r0.x; v.y += r0.y; v.z += r0.z; v.w += r0.w;
        }
        if (relu) {
          v.x = fmaxf(v.x, 0.f); v.y = fmaxf(v.y, 0.f);
          v.z = fmaxf(v.z, 0.f); v.w = fmaxf(v.w, 0.f);
        }
        *(float4*)(outF + offC + (size_t)rowg * ldc + colg) = v;
      }
    }
  }
}

// ---------------- cast x (fp32 -> bf16), 4 elems/thread ----------------
__global__ void cast_x_bf16(const float* __restrict__ in, bf16* __restrict__ out, int n4) {
  int i = blockIdx.x * 256 + threadIdx.x;
  if (i >= n4) return;
  float4 v = ((const float4*)in)[i];
  union { bf16 h[4]; float2 f; } u;
  u.h[0] = (bf16)v.x; u.h[1] = (bf16)v.y; u.h[2] = (bf16)v.z; u.h[3] = (bf16)v.w;
  ((float2*)out)[i] = u.f;
}

// ---------------- batched weight transpose+cast: fp32 [K][N] -> bf16 [N][K], 6 weights ----------------
struct WTList {
  const float* in[6];
  bf16* out[6];
  int K[6], N[6];
  int start[7];   // prefix sums of block counts
};
__global__ void transpose_cast_all(WTList L) {
  __shared__ float tile[32][33];
  int bid = blockIdx.x;
  int i = 0;
  while (bid >= L.start[i + 1]) ++i;
  int rel = bid - L.start[i];
  const int N = L.N[i], K = L.K[i];
  const int nx = N >> 5;
  const int n0 = (rel % nx) * 32, k0 = (rel / nx) * 32;
  const float* in = L.in[i];
  bf16* out = L.out[i];
  int tx = threadIdx.x, ty = threadIdx.y;
#pragma unroll
  for (int j = 0; j < 32; j += 8)
    tile[ty + j][tx] = in[(size_t)(k0 + ty + j) * N + n0 + tx];
  __syncthreads();
#pragma unroll
  for (int j = 0; j < 32; j += 8)
    out[(size_t)(n0 + ty + j) * K + k0 + tx] = (bf16)tile[tx][ty + j];
}

// ---------------- softmax over rows of 1024 bf16, in-place; one wave per row ----------------
__global__ void softmax_rows(bf16* __restrict__ sc) {
  int l = threadIdx.x & 63, w = threadIdx.x >> 6;
  size_t row = (size_t)blockIdx.x * 4 + w;
  float4* p4 = (float4*)(sc + row * SEQ);
  union U8 { float4 f; bf16 h[8]; };
  U8 u0, u1; u0.f = p4[l]; u1.f = p4[l + 64];
  float v[16];
  float mx = -1e30f;
#pragma unroll
  for (int i = 0; i < 8; ++i) { v[i] = (float)u0.h[i]; mx = fmaxf(mx, v[i]); }
#pragma unroll
  for (int i = 0; i < 8; ++i) { v[8 + i] = (float)u1.h[i]; mx = fmaxf(mx, v[8 + i]); }
#pragma unroll
  for (int d = 1; d < 64; d <<= 1) mx = fmaxf(mx, __shfl_xor(mx, d));
  float s = 0.0f;
#pragma unroll
  for (int i = 0; i < 16; ++i) { v[i] = __expf(v[i] - mx); s += v[i]; }
#pragma unroll
  for (int d = 1; d < 64; d <<= 1) s += __shfl_xor(s, d);
  float inv = 1.0f / s;
#pragma unroll
  for (int i = 0; i < 8; ++i) u0.h[i] = (bf16)(v[i] * inv);
#pragma unroll
  for (int i = 0; i < 8; ++i) u1.h[i] = (bf16)(v[8 + i] * inv);
  p4[l] = u0.f; p4[l + 64] = u1.f;
}

// ---------------- split-K reduce + residual + bias + layernorm, one wave per row ----------------
__global__ void reduce_ln(const float* __restrict__ parts, int ns,
                          const float* __restrict__ res, const float* __restrict__ bias,
                          const float* __restrict__ gw, const float* __restrict__ bw,
                          float* __restrict__ outF, bf16* __restrict__ outB) {
  int l = threadIdx.x & 63, w = threadIdx.x >> 6;
  int row = blockIdx.x * 4 + w;
  const long long pstr = (long long)MTOK * EBD;
  float4 a = {0.f, 0.f, 0.f, 0.f}, b = {0.f, 0.f, 0.f, 0.f};
  for (int s = 0; s < ns; ++s) {
    const float4* p = (const float4*)(parts + s * pstr + (size_t)row * EBD);
    float4 pa = p[l], pb = p[l + 64];
    a.x += pa.x; a.y += pa.y; a.z += pa.z; a.w += pa.w;
    b.x += pb.x; b.y += pb.y; b.z += pb.z; b.w += pb.w;
  }
  {
    const float4* p = (const float4*)(res + (size_t)row * EBD);
    float4 pa = p[l], pb = p[l + 64];
    a.x += pa.x; a.y += pa.y; a.z += pa.z; a.w += pa.w;
    b.x += pb.x; b.y += pb.y; b.z += pb.z; b.w += pb.w;
  }
  if (bias) {
    const float4* p = (const float4*)bias;
    float4 pa = p[l], pb = p[l + 64];
    a.x += pa.x; a.y += pa.y; a.z += pa.z; a.w += pa.w;
    b.x += pb.x; b.y += pb.y; b.z += pb.z; b.w += pb.w;
  }
  float s = a.x + a.y + a.z + a.w + b.x + b.y + b.z + b.w;
  float q = a.x * a.x + a.y * a.y + a.z * a.z + a.w * a.w
          + b.x * b.x + b.y * b.y + b.z * b.z + b.w * b.w;
#pragma unroll
  for (int d = 1; d < 64; d <<= 1) { s += __shfl_xor(s, d); q += __shfl_xor(q, d); }
  float mu = s * (1.0f / EBD);
  float var = q * (1.0f / EBD) - mu * mu;
  float rs = rsqrtf(var + 1e-5f);
  const float4* g4 = (const float4*)gw;
  const float4* b4 = (const float4*)bw;
  float4 ga = g4[l], gb = g4[l + 64], ba = b4[l], bb = b4[l + 64];
  float4 o0, o1;
  o0.x = (a.x - mu) * rs * ga.x + ba.x;
  o0.y = (a.y - mu) * rs * ga.y + ba.y;
  o0.z = (a.z - mu) * rs * ga.z + ba.z;
  o0.w = (a.w - mu) * rs * ga.w + ba.w;
  o1.x = (b.x - mu) * rs * gb.x + bb.x;
  o1.y = (b.y - mu) * rs * gb.y + bb.y;
  o1.z = (b.z - mu) * rs * gb.z + bb.z;
  o1.w = (b.w - mu) * rs * gb.w + bb.w;
  if (outF) {
    float4* q4 = (float4*)(outF + (size_t)row * EBD);
    q4[l] = o0; q4[l + 64] = o1;
  }
  if (outB) {
    union { bf16 h[4]; float2 f; } u0, u1;
    u0.h[0] = (bf16)o0.x; u0.h[1] = (bf16)o0.y; u0.h[2] = (bf16)o0.z; u0.h[3] = (bf16)o0.w;
    u1.h[0] = (bf16)o1.x; u1.h[1] = (bf16)o1.y; u1.h[2] = (bf16)o1.z; u1.h[3] = (bf16)o1.w;
    float2* r2 = (float2*)(outB + (size_t)row * EBD);
    r2[l] = u0.f; r2[l + 64] = u1.f;
  }
}

// ---------------- host-side orchestration ----------------
extern "C" void kernel_launch(void* const* d_in, const int* in_sizes, int n_in,
                              void* d_out, int out_size, void* d_ws, size_t ws_size,
                              hipStream_t stream) {
  const float* x  = (const float*)d_in[0];
  const float* Wq = (const float*)d_in[1];
  const float* Wk = (const float*)d_in[2];
  const float* Wv = (const float*)d_in[3];
  const float* Wo = (const float*)d_in[4];
  const float* g1 = (const float*)d_in[5];
  const float* b1 = (const float*)d_in[6];
  const float* g2 = (const float*)d_in[7];
  const float* b2 = (const float*)d_in[8];
  const float* W1 = (const float*)d_in[9];
  const float* c1 = (const float*)d_in[10];
  const float* W2 = (const float*)d_in[11];
  const float* c2 = (const float*)d_in[12];
  float* out = (float*)d_out;

  char* p = (char*)d_ws;
  auto take = [&](size_t bytes) { char* r = p; p += (bytes + 255) & ~(size_t)255; return r; };
  bf16*  xb    = (bf16*) take((size_t)MTOK * EBD * 2);            //   4 MB
  bf16*  qk    = (bf16*) take((size_t)MTOK * 2 * HE * 2);         //  64 MB [4096][8192]
  bf16*  vT    = (bf16*) take((size_t)32 * EBD * SEQ * 2);        //  32 MB [(b,h)][e][s]
  bf16*  sc    = (bf16*) take((size_t)32 * SEQ * SEQ * 2);        //  64 MB (split-K fp32 partials overlay)
  bf16*  ao    = (bf16*) take((size_t)MTOK * HE * 2);             //  32 MB
  float* nF    = (float*)take((size_t)MTOK * EBD * 4);            //   8 MB
  bf16*  nB    = (bf16*) take((size_t)MTOK * EBD * 2);            //   4 MB
  bf16*  hb    = (bf16*) take((size_t)MTOK * FFD * 2);            //  16 MB
  bf16*  WqkvT = (bf16*) take((size_t)3 * HE * EBD * 2);          //  12 MB [12288][512]
  bf16*  WoT   = (bf16*) take((size_t)EBD * HE * 2);              //   4 MB
  bf16*  W1T   = (bf16*) take((size_t)FFD * EBD * 2);             //   2 MB
  bf16*  W2T   = (bf16*) take((size_t)EBD * FFD * 2);             //   2 MB   total ~244 MB
  float* parts = (float*)sc;       // split-K partials overlay (sc dead by then)

  auto gemm = [&](const bf16* A, const bf16* Bt, float* oF, bf16* oB, bf16* vTo,
                  const float* bias, const float* res,
                  int Mm, int Nn, int Kk, int lda, int ldb, int ldc, int ldr,
                  long long bAb, long long bAh, long long bBb, long long bBh,
                  long long bCb, long long bCh, int zdiv, int batch,
                  float scale, int relu, int vmode) {
    dim3 g(Nn / 128, Mm / 128, batch);
    gemm_bt<<<g, dim3(256), 0, stream>>>(A, Bt, oF, oB, vTo, bias, res,
        lda, ldb, ldc, ldr, Kk, bAb, bAh, bBb, bBh, bCb, bCh, zdiv, scale, relu, vmode);
  };

  // --- preprocessing: bf16 cast + ONE batched weight-transpose dispatch ---
  cast_x_bf16<<<dim3((MTOK * EBD / 4 + 255) / 256), dim3(256), 0, stream>>>(x, xb, MTOK * EBD / 4);
  {
    WTList L;
    const float* ins[6] = {Wq, Wk, Wv, Wo, W1, W2};
    bf16* outs[6] = {WqkvT, WqkvT + (size_t)HE * EBD, WqkvT + (size_t)2 * HE * EBD, WoT, W1T, W2T};
    int Ks[6] = {EBD, EBD, EBD, HE, EBD, FFD};
    int Ns[6] = {HE, HE, HE, EBD, FFD, EBD};
    int acc = 0;
    for (int i = 0; i < 6; ++i) {
      L.in[i] = ins[i]; L.out[i] = outs[i]; L.K[i] = Ks[i]; L.N[i] = Ns[i];
      L.start[i] = acc;
      acc += (Ks[i] / 32) * (Ns[i] / 32);
    }
    L.start[6] = acc;   // 10240 blocks total
    transpose_cast_all<<<dim3(acc), dim3(32, 8), 0, stream>>>(L);
  }

  // --- fused QKV projection: q,k -> qk [4096][8192]; V -> vT transposed in-epilogue ---
  gemm(xb, WqkvT, nullptr, qk, vT, nullptr, nullptr, MTOK, 3 * HE, EBD,
       EBD, EBD, 2 * HE, 0, 0, 0, 0, 0, 0, 0, 64, 1, 1.0f, 0, 1);

  // --- scores = (q @ k^T) * 1/sqrt(E), batched over 32 (b,h) ---
  const float qs = 0.04419417382415922f;  // 1/sqrt(512)
  gemm(qk, qk + HE, nullptr, sc, nullptr, nullptr, nullptr, SEQ, SEQ, EBD,
       2 * HE, 2 * HE, SEQ, 0,
       (long long)SEQ * 2 * HE, EBD, (long long)SEQ * 2 * HE, EBD,
       (long long)8 * SEQ * SEQ, (long long)SEQ * SEQ, 8, 32, qs, 0, 0);

  softmax_rows<<<dim3(32 * SEQ / 4), dim3(256), 0, stream>>>(sc);

  // --- attn @ v, batched; ao [4096][4096] ---
  gemm(sc, vT, nullptr, ao, nullptr, nullptr, nullptr, SEQ, EBD, SEQ,
       SEQ, SEQ, HE, 0,
       (long long)8 * SEQ * SEQ, (long long)SEQ * SEQ,
       (long long)8 * EBD * SEQ, (long long)EBD * SEQ,
       (long long)SEQ * HE, (long long)EBD, 8, 32, 1.0f, 0, 0);

  // --- out @ Wo, split-K x4 (K=4096 -> 4x1024) -> fp32 partials; reduce + x + LN1 ---
  gemm(ao, WoT, parts, nullptr, nullptr, nullptr, nullptr, MTOK, EBD, 1024,
       HE, HE, EBD, 0,
       0, 1024, 0, 1024, 0, (long long)MTOK * EBD, 64, 4, 1.0f, 0, 0);
  reduce_ln<<<dim3(MTOK / 4), dim3(256), 0, stream>>>(parts, 4, x, nullptr, g1, b1, nF, nB);

  // --- FF1: h = relu(normed @ W1 + c1) ---
  gemm(nB, W1T, nullptr, hb, nullptr, c1, nullptr, MTOK, FFD, EBD,
       EBD, EBD, FFD, 0, 0, 0, 0, 0, 0, 0, 64, 1, 1.0f, 1, 0);

  // --- FF2: split-K x4 (K=2048 -> 4x512) -> partials; reduce + c2 + nF + LN2 ---
  gemm(hb, W2T, parts, nullptr, nullptr, nullptr, nullptr, MTOK, EBD, 512,
       FFD, FFD, EBD, 0,
       0, 512, 0, 512, 0, (long long)MTOK * EBD, 64, 4, 1.0f, 0, 0);
  reduce_ln<<<dim3(MTOK / 4), dim3(256), 0, stream>>>(parts, 4, nF, c2, g2, b2, out, nullptr);
}

// Round 5
// 380.010 us; speedup vs baseline: 1.5550x; 1.1141x over previous
//
#include <hip/hip_runtime.h>

// ---------------- constants for this problem ----------------
#define EBD   512      // embed size (= head dim here)
#define NHEAD 8
#define BSZ   4
#define SEQ   1024
#define MTOK  4096     // B*S tokens
#define HE    4096     // H*E
#define FFD   2048     // 4*E

typedef __bf16 bf16;
typedef __attribute__((ext_vector_type(8))) __bf16 bf16x8;
typedef __attribute__((ext_vector_type(4))) float  f32x4;

// async global->LDS, 16B per lane; LDS dest must be wave-uniform base + lane*16
__device__ __forceinline__ void async_load16(const void* g, void* l) {
  __builtin_amdgcn_global_load_lds(
      (const __attribute__((address_space(1))) void*)g,
      (__attribute__((address_space(3))) void*)l, 16, 0, 0);
}

// ---------------- GEMM: C = A @ Bt^T  (A: MxK row-major, Bt: NxK row-major) ----------------
// 128x128 tile, BK=64, 256 threads (4 waves, each 64x64 via 4x4 of 16x16x32 MFMA).
// LDS tiles are [row][64] bf16 (row stride 128 B = bank period) with XOR chunk swizzle:
// physical 16B-chunk p of row r holds global chunk g = p ^ ((r>>1)&7). Staging thread t
// (call j) covers row j*32+(t>>3), phys chunk t&7 -> fetches global chunk (t&7)^((t>>4)&7);
// 8 consecutive threads still cover one full 128B row segment (coalesced). Fragment
// ds_read_b128 then hits each bank-quad exactly 2x per 16 lanes (2-way = free, m136).
// Batch/split-K via blockIdx.z: zb=z/zdiv, zh=z%zdiv; offsets zb*bXb+zh*bXh (elements).
// LDS: single 36864B block; As(16K)+Bs(16K) overlaid with epilogue stage Cs[4][2304].
__global__ void gemm_bt(const bf16* __restrict__ A, const bf16* __restrict__ Bt,
                        float* __restrict__ outF, bf16* __restrict__ outB,
                        bf16* __restrict__ vTout,
                        const float* __restrict__ bias, const float* __restrict__ res,
                        int lda, int ldb, int ldc, int ldr, int K,
                        long long bAb, long long bAh, long long bBb, long long bBh,
                        long long bCb, long long bCh, int zdiv,
                        float scale, int relu, int vmode)
{
  __shared__ __attribute__((aligned(16))) float Smem[4 * 2304];  // 36864 B
  bf16* As = (bf16*)Smem;               // 128*64 bf16 = 16 KB
  bf16* Bs = (bf16*)Smem + 128 * 64;    // next 16 KB

  const int t = threadIdx.x;
  const int w = t >> 6, l = t & 63;
  const int m0 = blockIdx.y * 128, n0 = blockIdx.x * 128;
  const int z = blockIdx.z;
  const int zb = z / zdiv, zh = z - zb * zdiv;

  const bf16* Ab = A + (size_t)zb * bAb + (size_t)zh * bAh;
  const bf16* Bb = Bt + (size_t)zb * bBb + (size_t)zh * bBh;

  // staging map (BK=64): call j: row = j*32 + (t>>3), global chunk = (t&7)^((t>>4)&7)
  const int srow = t >> 3;                              // 0..31
  const int gch  = (((t & 7) ^ ((t >> 4) & 7))) * 8;    // k element offset of 16B chunk
  const bf16* pA = Ab + (size_t)(m0 + srow) * lda + gch;
  const bf16* pB = Bb + (size_t)(n0 + srow) * ldb + gch;
  const size_t ldA32 = (size_t)32 * lda;
  const size_t ldB32 = (size_t)32 * ldb;

  // LDS dests: call j writes byte range j*4096 + t*16 -> wave-uniform base + lane*16
  bf16* ldsA = As + w * 512;           // + j*2048 elems per call
  bf16* ldsB = Bs + w * 512;

  const int wm = (w >> 1) * 64, wn = (w & 1) * 64;
  const int lr = l & 15;               // A-row / B-col within 16
  const int lc = l >> 4;               // k-chunk index within 32 (0..3)

  f32x4 acc[4][4];
#pragma unroll
  for (int i = 0; i < 4; ++i)
#pragma unroll
    for (int j = 0; j < 4; ++j) { f32x4 zv = {0.f, 0.f, 0.f, 0.f}; acc[i][j] = zv; }

  const int nkt = K >> 6;
  for (int kt = 0; kt < nkt; ++kt) {
    __syncthreads();                   // previous iteration's ds_reads done
#pragma unroll
    for (int j = 0; j < 4; ++j) {
      async_load16(pA + j * ldA32, ldsA + j * 2048);
      async_load16(pB + j * ldB32, ldsB + j * 2048);
    }
    pA += 64; pB += 64;
    __syncthreads();                   // staging complete (vmcnt drained)
#pragma unroll
    for (int ks = 0; ks < 2; ++ks) {
      bf16x8 af[4], bv[4];
#pragma unroll
      for (int i = 0; i < 4; ++i) {
        const int row = wm + i * 16 + lr;
        const int p = (ks * 4 + lc) ^ ((row >> 1) & 7);
        af[i] = *(const bf16x8*)&As[row * 64 + p * 8];
      }
#pragma unroll
      for (int i = 0; i < 4; ++i) {
        const int row = wn + i * 16 + lr;
        const int p = (ks * 4 + lc) ^ ((row >> 1) & 7);
        bv[i] = *(const bf16x8*)&Bs[row * 64 + p * 8];
      }
#pragma unroll
      for (int mi = 0; mi < 4; ++mi)
#pragma unroll
        for (int ni = 0; ni < 4; ++ni)
          acc[mi][ni] = __builtin_amdgcn_mfma_f32_16x16x32_bf16(af[mi], bv[ni], acc[mi][ni], 0, 0, 0);
    }
  }

  // ---- LDS-staged epilogue (C/D layout: col=lane&15, row=(lane>>4)*4+r) ----
  float* cs = Smem + w * 2304;         // 64x36 fp32 per wave (overlays As/Bs)
  const size_t offC = (size_t)zb * bCb + (size_t)zh * bCh;
  const int rq = (l >> 4) * 4;         // reg-group row base

  if (vmode && n0 >= 8192) {
    // ---- V-projection tiles: store transposed into vT[(b*8+h)][e][s] ----
    const int b  = (m0 + wm) >> 10;
    const int s0 = (m0 + wm) & 1023;
#pragma unroll
    for (int p = 0; p < 2; ++p) {
      __syncthreads();
#pragma unroll
      for (int ni2 = 0; ni2 < 2; ++ni2) {
        const int ni = 2 * p + ni2;
        const int cl = ni2 * 16 + lr;
#pragma unroll
        for (int mi = 0; mi < 4; ++mi)
#pragma unroll
          for (int r = 0; r < 4; ++r)
            cs[cl * 68 + mi * 16 + rq + r] = acc[mi][ni][r];  // transposed: [col][row]
      }
      __syncthreads();
      const int c = l & 31, half = l >> 5;
      int e = (n0 - 8192) + wn + p * 32 + c;
      const int h = e >> 9; e &= 511;
      bf16* dst = vTout + (((size_t)(b * 8 + h) * 512 + e) << 10) + s0 + half * 32;
      float vv[32];
#pragma unroll
      for (int j = 0; j < 8; ++j)
        *(f32x4*)&vv[4 * j] = *(const f32x4*)&cs[c * 68 + half * 32 + 4 * j];
#pragma unroll
      for (int q4 = 0; q4 < 4; ++q4) {
        union { bf16 h8[8]; float4 f; } u;
#pragma unroll
        for (int j = 0; j < 8; ++j) u.h8[j] = (bf16)vv[q4 * 8 + j];
        *(float4*)(dst + q4 * 8) = u.f;
      }
    }
    return;
  }

#pragma unroll
  for (int p = 0; p < 2; ++p) {
    __syncthreads();
#pragma unroll
    for (int ni2 = 0; ni2 < 2; ++ni2) {
      const int ni = 2 * p + ni2;
      const int cl = ni2 * 16 + lr;
#pragma unroll
      for (int mi = 0; mi < 4; ++mi)
#pragma unroll
        for (int r = 0; r < 4; ++r)
          cs[(mi * 16 + rq + r) * 36 + cl] = acc[mi][ni][r];
    }
    __syncthreads();
    if (outB) {
      // bf16 output: lane packs 8 consecutive cols of one row -> 16B store
      const int rl0 = l >> 2, c8 = (l & 3) * 8;
#pragma unroll
      for (int sub = 0; sub < 4; ++sub) {
        const int rl = sub * 16 + rl0;
        const int rowg = m0 + wm + rl;
        const int colg = n0 + wn + p * 32 + c8;
        float vv[8];
        *(f32x4*)&vv[0] = *(const f32x4*)&cs[rl * 36 + c8];
        *(f32x4*)&vv[4] = *(const f32x4*)&cs[rl * 36 + c8 + 4];
#pragma unroll
        for (int j = 0; j < 8; ++j) vv[j] *= scale;
        if (bias) {
          const float4 b0 = *(const float4*)(bias + colg);
          const float4 b1 = *(const float4*)(bias + colg + 4);
          vv[0] += b0.x; vv[1] += b0.y; vv[2] += b0.z; vv[3] += b0.w;
          vv[4] += b1.x; vv[5] += b1.y; vv[6] += b1.z; vv[7] += b1.w;
        }
        if (res) {
          const float4 r0 = *(const float4*)(res + (size_t)rowg * ldr + colg);
          const float4 r1 = *(const float4*)(res + (size_t)rowg * ldr + colg + 4);
          vv[0] += r0.x; vv[1] += r0.y; vv[2] += r0.z; vv[3] += r0.w;
          vv[4] += r1.x; vv[5] += r1.y; vv[6] += r1.z; vv[7] += r1.w;
        }
        if (relu)
#pragma unroll
          for (int j = 0; j < 8; ++j) vv[j] = fmaxf(vv[j], 0.0f);
        union { bf16 h8[8]; float4 f; } u;
#pragma unroll
        for (int j = 0; j < 8; ++j) u.h8[j] = (bf16)vv[j];
        *(float4*)(outB + offC + (size_t)rowg * ldc + colg) = u.f;
      }
    } else {
      // f32 output (split-K partials): lane stores float4
      const int rl0 = l >> 3, c4 = (l & 7) * 4;
#pragma unroll
      for (int sub = 0; sub < 8; ++sub) {
        const int rl = sub * 8 + rl0;
        const int rowg = m0 + wm + rl;
        const int colg = n0 + wn + p * 32 + c4;
        float4 v = *(const float4*)&cs[rl * 36 + c4];
        v.x *= scale; v.y *= scale; v.z *= scale; v.w *= scale;
        if (bias) {
          const float4 b0 = *(const float4*)(bias + colg);
          v.x += b0.x; v.y += b0.y; v.z += b0.z; v.w += b0.w;
        }
        if (res) {
          const float4 r0 = *(const float4*)(res + (size_t)rowg * ldr + colg);
          v.x += r0.x; v.y += r0.y; v.z += r0.z; v.w += r0.w;
        }
        if (relu) {
          v.x = fmaxf(v.x, 0.f); v.y = fmaxf(v.y, 0.f);
          v.z = fmaxf(v.z, 0.f); v.w = fmaxf(v.w, 0.f);
        }
        *(float4*)(outF + offC + (size_t)rowg * ldc + colg) = v;
      }
    }
  }
}

// ---------------- cast x (fp32 -> bf16), 4 elems/thread ----------------
__global__ void cast_x_bf16(const float* __restrict__ in, bf16* __restrict__ out, int n4) {
  int i = blockIdx.x * 256 + threadIdx.x;
  if (i >= n4) return;
  float4 v = ((const float4*)in)[i];
  union { bf16 h[4]; float2 f; } u;
  u.h[0] = (bf16)v.x; u.h[1] = (bf16)v.y; u.h[2] = (bf16)v.z; u.h[3] = (bf16)v.w;
  ((float2*)out)[i] = u.f;
}

// ---------------- batched weight transpose+cast: fp32 [K][N] -> bf16 [N][K], 6 weights ----------------
struct WTList {
  const float* in[6];
  bf16* out[6];
  int K[6], N[6];
  int start[7];   // prefix sums of block counts
};
__global__ void transpose_cast_all(WTList L) {
  __shared__ float tile[32][33];
  int bid = blockIdx.x;
  int i = 0;
  while (bid >= L.start[i + 1]) ++i;
  int rel = bid - L.start[i];
  const int N = L.N[i], K = L.K[i];
  const int nx = N >> 5;
  const int n0 = (rel % nx) * 32, k0 = (rel / nx) * 32;
  const float* in = L.in[i];
  bf16* out = L.out[i];
  int tx = threadIdx.x, ty = threadIdx.y;
#pragma unroll
  for (int j = 0; j < 32; j += 8)
    tile[ty + j][tx] = in[(size_t)(k0 + ty + j) * N + n0 + tx];
  __syncthreads();
#pragma unroll
  for (int j = 0; j < 32; j += 8)
    out[(size_t)(n0 + ty + j) * K + k0 + tx] = (bf16)tile[tx][ty + j];
}

// ---------------- softmax over rows of 1024 bf16, in-place; one wave per row ----------------
__global__ void softmax_rows(bf16* __restrict__ sc) {
  int l = threadIdx.x & 63, w = threadIdx.x >> 6;
  size_t row = (size_t)blockIdx.x * 4 + w;
  float4* p4 = (float4*)(sc + row * SEQ);
  union U8 { float4 f; bf16 h[8]; };
  U8 u0, u1; u0.f = p4[l]; u1.f = p4[l + 64];
  float v[16];
  float mx = -1e30f;
#pragma unroll
  for (int i = 0; i < 8; ++i) { v[i] = (float)u0.h[i]; mx = fmaxf(mx, v[i]); }
#pragma unroll
  for (int i = 0; i < 8; ++i) { v[8 + i] = (float)u1.h[i]; mx = fmaxf(mx, v[8 + i]); }
#pragma unroll
  for (int d = 1; d < 64; d <<= 1) mx = fmaxf(mx, __shfl_xor(mx, d));
  float s = 0.0f;
#pragma unroll
  for (int i = 0; i < 16; ++i) { v[i] = __expf(v[i] - mx); s += v[i]; }
#pragma unroll
  for (int d = 1; d < 64; d <<= 1) s += __shfl_xor(s, d);
  float inv = 1.0f / s;
#pragma unroll
  for (int i = 0; i < 8; ++i) u0.h[i] = (bf16)(v[i] * inv);
#pragma unroll
  for (int i = 0; i < 8; ++i) u1.h[i] = (bf16)(v[8 + i] * inv);
  p4[l] = u0.f; p4[l + 64] = u1.f;
}

// ---------------- split-K reduce + residual + bias + layernorm, one wave per row ----------------
__global__ void reduce_ln(const float* __restrict__ parts, int ns,
                          const float* __restrict__ res, const float* __restrict__ bias,
                          const float* __restrict__ gw, const float* __restrict__ bw,
                          float* __restrict__ outF, bf16* __restrict__ outB) {
  int l = threadIdx.x & 63, w = threadIdx.x >> 6;
  int row = blockIdx.x * 4 + w;
  const long long pstr = (long long)MTOK * EBD;
  float4 a = {0.f, 0.f, 0.f, 0.f}, b = {0.f, 0.f, 0.f, 0.f};
  for (int s = 0; s < ns; ++s) {
    const float4* p = (const float4*)(parts + s * pstr + (size_t)row * EBD);
    float4 pa = p[l], pb = p[l + 64];
    a.x += pa.x; a.y += pa.y; a.z += pa.z; a.w += pa.w;
    b.x += pb.x; b.y += pb.y; b.z += pb.z; b.w += pb.w;
  }
  {
    const float4* p = (const float4*)(res + (size_t)row * EBD);
    float4 pa = p[l], pb = p[l + 64];
    a.x += pa.x; a.y += pa.y; a.z += pa.z; a.w += pa.w;
    b.x += pb.x; b.y += pb.y; b.z += pb.z; b.w += pb.w;
  }
  if (bias) {
    const float4* p = (const float4*)bias;
    float4 pa = p[l], pb = p[l + 64];
    a.x += pa.x; a.y += pa.y; a.z += pa.z; a.w += pa.w;
    b.x += pb.x; b.y += pb.y; b.z += pb.z; b.w += pb.w;
  }
  float s = a.x + a.y + a.z + a.w + b.x + b.y + b.z + b.w;
  float q = a.x * a.x + a.y * a.y + a.z * a.z + a.w * a.w
          + b.x * b.x + b.y * b.y + b.z * b.z + b.w * b.w;
#pragma unroll
  for (int d = 1; d < 64; d <<= 1) { s += __shfl_xor(s, d); q += __shfl_xor(q, d); }
  float mu = s * (1.0f / EBD);
  float var = q * (1.0f / EBD) - mu * mu;
  float rs = rsqrtf(var + 1e-5f);
  const float4* g4 = (const float4*)gw;
  const float4* b4 = (const float4*)bw;
  float4 ga = g4[l], gb = g4[l + 64], ba = b4[l], bb = b4[l + 64];
  float4 o0, o1;
  o0.x = (a.x - mu) * rs * ga.x + ba.x;
  o0.y = (a.y - mu) * rs * ga.y + ba.y;
  o0.z = (a.z - mu) * rs * ga.z + ba.z;
  o0.w = (a.w - mu) * rs * ga.w + ba.w;
  o1.x = (b.x - mu) * rs * gb.x + bb.x;
  o1.y = (b.y - mu) * rs * gb.y + bb.y;
  o1.z = (b.z - mu) * rs * gb.z + bb.z;
  o1.w = (b.w - mu) * rs * gb.w + bb.w;
  if (outF) {
    float4* q4 = (float4*)(outF + (size_t)row * EBD);
    q4[l] = o0; q4[l + 64] = o1;
  }
  if (outB) {
    union { bf16 h[4]; float2 f; } u0, u1;
    u0.h[0] = (bf16)o0.x; u0.h[1] = (bf16)o0.y; u0.h[2] = (bf16)o0.z; u0.h[3] = (bf16)o0.w;
    u1.h[0] = (bf16)o1.x; u1.h[1] = (bf16)o1.y; u1.h[2] = (bf16)o1.z; u1.h[3] = (bf16)o1.w;
    float2* r2 = (float2*)(outB + (size_t)row * EBD);
    r2[l] = u0.f; r2[l + 64] = u1.f;
  }
}

// ---------------- host-side orchestration ----------------
extern "C" void kernel_launch(void* const* d_in, const int* in_sizes, int n_in,
                              void* d_out, int out_size, void* d_ws, size_t ws_size,
                              hipStream_t stream) {
  const float* x  = (const float*)d_in[0];
  const float* Wq = (const float*)d_in[1];
  const float* Wk = (const float*)d_in[2];
  const float* Wv = (const float*)d_in[3];
  const float* Wo = (const float*)d_in[4];
  const float* g1 = (const float*)d_in[5];
  const float* b1 = (const float*)d_in[6];
  const float* g2 = (const float*)d_in[7];
  const float* b2 = (const float*)d_in[8];
  const float* W1 = (const float*)d_in[9];
  const float* c1 = (const float*)d_in[10];
  const float* W2 = (const float*)d_in[11];
  const float* c2 = (const float*)d_in[12];
  float* out = (float*)d_out;

  char* p = (char*)d_ws;
  auto take = [&](size_t bytes) { char* r = p; p += (bytes + 255) & ~(size_t)255; return r; };
  bf16*  xb    = (bf16*) take((size_t)MTOK * EBD * 2);            //   4 MB
  bf16*  qk    = (bf16*) take((size_t)MTOK * 2 * HE * 2);         //  64 MB [4096][8192]
  bf16*  vT    = (bf16*) take((size_t)32 * EBD * SEQ * 2);        //  32 MB [(b,h)][e][s]
  bf16*  sc    = (bf16*) take((size_t)32 * SEQ * SEQ * 2);        //  64 MB (split-K fp32 partials overlay)
  bf16*  ao    = (bf16*) take((size_t)MTOK * HE * 2);             //  32 MB
  float* nF    = (float*)take((size_t)MTOK * EBD * 4);            //   8 MB
  bf16*  nB    = (bf16*) take((size_t)MTOK * EBD * 2);            //   4 MB
  bf16*  hb    = (bf16*) take((size_t)MTOK * FFD * 2);            //  16 MB
  bf16*  WqkvT = (bf16*) take((size_t)3 * HE * EBD * 2);          //  12 MB [12288][512]
  bf16*  WoT   = (bf16*) take((size_t)EBD * HE * 2);              //   4 MB
  bf16*  W1T   = (bf16*) take((size_t)FFD * EBD * 2);             //   2 MB
  bf16*  W2T   = (bf16*) take((size_t)EBD * FFD * 2);             //   2 MB   total ~244 MB
  float* parts = (float*)sc;       // split-K partials overlay (sc dead by then)

  auto gemm = [&](const bf16* A, const bf16* Bt, float* oF, bf16* oB, bf16* vTo,
                  const float* bias, const float* res,
                  int Mm, int Nn, int Kk, int lda, int ldb, int ldc, int ldr,
                  long long bAb, long long bAh, long long bBb, long long bBh,
                  long long bCb, long long bCh, int zdiv, int batch,
                  float scale, int relu, int vmode) {
    dim3 g(Nn / 128, Mm / 128, batch);
    gemm_bt<<<g, dim3(256), 0, stream>>>(A, Bt, oF, oB, vTo, bias, res,
        lda, ldb, ldc, ldr, Kk, bAb, bAh, bBb, bBh, bCb, bCh, zdiv, scale, relu, vmode);
  };

  // --- preprocessing: bf16 cast + ONE batched weight-transpose dispatch ---
  cast_x_bf16<<<dim3((MTOK * EBD / 4 + 255) / 256), dim3(256), 0, stream>>>(x, xb, MTOK * EBD / 4);
  {
    WTList L;
    const float* ins[6] = {Wq, Wk, Wv, Wo, W1, W2};
    bf16* outs[6] = {WqkvT, WqkvT + (size_t)HE * EBD, WqkvT + (size_t)2 * HE * EBD, WoT, W1T, W2T};
    int Ks[6] = {EBD, EBD, EBD, HE, EBD, FFD};
    int Ns[6] = {HE, HE, HE, EBD, FFD, EBD};
    int acc = 0;
    for (int i = 0; i < 6; ++i) {
      L.in[i] = ins[i]; L.out[i] = outs[i]; L.K[i] = Ks[i]; L.N[i] = Ns[i];
      L.start[i] = acc;
      acc += (Ks[i] / 32) * (Ns[i] / 32);
    }
    L.start[6] = acc;   // 10240 blocks total
    transpose_cast_all<<<dim3(acc), dim3(32, 8), 0, stream>>>(L);
  }

  // --- fused QKV projection: q,k -> qk [4096][8192]; V -> vT transposed in-epilogue ---
  gemm(xb, WqkvT, nullptr, qk, vT, nullptr, nullptr, MTOK, 3 * HE, EBD,
       EBD, EBD, 2 * HE, 0, 0, 0, 0, 0, 0, 0, 64, 1, 1.0f, 0, 1);

  // --- scores = (q @ k^T) * 1/sqrt(E), batched over 32 (b,h) ---
  const float qs = 0.04419417382415922f;  // 1/sqrt(512)
  gemm(qk, qk + HE, nullptr, sc, nullptr, nullptr, nullptr, SEQ, SEQ, EBD,
       2 * HE, 2 * HE, SEQ, 0,
       (long long)SEQ * 2 * HE, EBD, (long long)SEQ * 2 * HE, EBD,
       (long long)8 * SEQ * SEQ, (long long)SEQ * SEQ, 8, 32, qs, 0, 0);

  softmax_rows<<<dim3(32 * SEQ / 4), dim3(256), 0, stream>>>(sc);

  // --- attn @ v, batched; ao [4096][4096] ---
  gemm(sc, vT, nullptr, ao, nullptr, nullptr, nullptr, SEQ, EBD, SEQ,
       SEQ, SEQ, HE, 0,
       (long long)8 * SEQ * SEQ, (long long)SEQ * SEQ,
       (long long)8 * EBD * SEQ, (long long)EBD * SEQ,
       (long long)SEQ * HE, (long long)EBD, 8, 32, 1.0f, 0, 0);

  // --- out @ Wo, split-K x4 (K=4096 -> 4x1024) -> fp32 partials; reduce + x + LN1 ---
  gemm(ao, WoT, parts, nullptr, nullptr, nullptr, nullptr, MTOK, EBD, 1024,
       HE, HE, EBD, 0,
       0, 1024, 0, 1024, 0, (long long)MTOK * EBD, 64, 4, 1.0f, 0, 0);
  reduce_ln<<<dim3(MTOK / 4), dim3(256), 0, stream>>>(parts, 4, x, nullptr, g1, b1, nF, nB);

  // --- FF1: h = relu(normed @ W1 + c1) ---
  gemm(nB, W1T, nullptr, hb, nullptr, c1, nullptr, MTOK, FFD, EBD,
       EBD, EBD, FFD, 0, 0, 0, 0, 0, 0, 0, 64, 1, 1.0f, 1, 0);

  // --- FF2: split-K x4 (K=2048 -> 4x512) -> partials; reduce + c2 + nF + LN2 ---
  gemm(hb, W2T, parts, nullptr, nullptr, nullptr, nullptr, MTOK, EBD, 512,
       FFD, FFD, EBD, 0,
       0, 512, 0, 512, 0, (long long)MTOK * EBD, 64, 4, 1.0f, 0, 0);
  reduce_ln<<<dim3(MTOK / 4), dim3(256), 0, stream>>>(parts, 4, nF, c2, g2, b2, out, nullptr);
}

// Round 6
// 296.893 us; speedup vs baseline: 1.9903x; 1.2800x over previous
//
#include <hip/hip_runtime.h>
#include <hip/hip_fp8.h>

// ---------------- constants for this problem ----------------
#define EBD   512      // embed size (= head dim here)
#define NHEAD 8
#define BSZ   4
#define SEQ   1024
#define MTOK  4096     // B*S tokens
#define HE    4096     // H*E
#define FFD   2048     // 4*E

typedef __bf16 bf16;
typedef __attribute__((ext_vector_type(8))) __bf16 bf16x8;
typedef __attribute__((ext_vector_type(4))) float  f32x4;
typedef __attribute__((ext_vector_type(8))) int    i32x8;

// async global->LDS, 16B per lane; LDS dest must be wave-uniform base + lane*16
__device__ __forceinline__ void async_load16(const void* g, void* l) {
  __builtin_amdgcn_global_load_lds(
      (const __attribute__((address_space(1))) void*)g,
      (__attribute__((address_space(3))) void*)l, 16, 0, 0);
}

// ---------------- fp8 e4m3 (OCP) convert helpers ----------------
#if __has_builtin(__builtin_amdgcn_cvt_pk_fp8_f32)
__device__ __forceinline__ int pk_fp8_lo(float a, float b, int old) {
  return __builtin_amdgcn_cvt_pk_fp8_f32(a, b, old, false);
}
__device__ __forceinline__ int pk_fp8_hi(float a, float b, int old) {
  return __builtin_amdgcn_cvt_pk_fp8_f32(a, b, old, true);
}
#else
__device__ __forceinline__ int pk_fp8_lo(float a, float b, int old) {
  __hip_fp8_e4m3 fa(a), fb(b);
  int w = (int)fa.__x | ((int)fb.__x << 8);
  return (old & ~0xffff) | w;
}
__device__ __forceinline__ int pk_fp8_hi(float a, float b, int old) {
  __hip_fp8_e4m3 fa(a), fb(b);
  int w = (int)fa.__x | ((int)fb.__x << 8);
  return (old & 0xffff) | (w << 16);
}
#endif

#if __has_builtin(__builtin_amdgcn_cvt_f32_fp8)
#define F8DEC(v, k) __builtin_amdgcn_cvt_f32_fp8((v), (k))
#else
__device__ __forceinline__ float __f8dec_sw(int v, int k) {
  __hip_fp8_e4m3 f; f.__x = (unsigned char)((v >> (8 * k)) & 0xff); return (float)f;
}
#define F8DEC(v, k) __f8dec_sw((v), (k))
#endif

__device__ __forceinline__ int4 pack16_fp8(const float* v) {
  int4 r;
  r.x = pk_fp8_hi(v[2],  v[3],  pk_fp8_lo(v[0],  v[1],  0));
  r.y = pk_fp8_hi(v[6],  v[7],  pk_fp8_lo(v[4],  v[5],  0));
  r.z = pk_fp8_hi(v[10], v[11], pk_fp8_lo(v[8],  v[9],  0));
  r.w = pk_fp8_hi(v[14], v[15], pk_fp8_lo(v[12], v[13], 0));
  return r;
}

// ---------------- bf16 GEMM (round-5 kernel, unchanged): C = A @ Bt^T ----------------
// 128x128 tile, BK=64, XOR chunk swizzle, LDS-staged epilogue; used for FF1/FF2.
__global__ void gemm_bt(const bf16* __restrict__ A, const bf16* __restrict__ Bt,
                        float* __restrict__ outF, bf16* __restrict__ outB,
                        const float* __restrict__ bias, const float* __restrict__ res,
                        int lda, int ldb, int ldc, int ldr, int K,
                        long long bAb, long long bAh, long long bBb, long long bBh,
                        long long bCb, long long bCh, int zdiv,
                        float scale, int relu)
{
  __shared__ __attribute__((aligned(16))) float Smem[4 * 2304];  // 36864 B
  bf16* As = (bf16*)Smem;               // 128*64 bf16 = 16 KB
  bf16* Bs = (bf16*)Smem + 128 * 64;    // next 16 KB

  const int t = threadIdx.x;
  const int w = t >> 6, l = t & 63;
  const int m0 = blockIdx.y * 128, n0 = blockIdx.x * 128;
  const int z = blockIdx.z;
  const int zb = z / zdiv, zh = z - zb * zdiv;

  const bf16* Ab = A + (size_t)zb * bAb + (size_t)zh * bAh;
  const bf16* Bb = Bt + (size_t)zb * bBb + (size_t)zh * bBh;

  const int srow = t >> 3;                              // 0..31
  const int gch  = (((t & 7) ^ ((t >> 4) & 7))) * 8;    // k element offset of 16B chunk
  const bf16* pA = Ab + (size_t)(m0 + srow) * lda + gch;
  const bf16* pB = Bb + (size_t)(n0 + srow) * ldb + gch;
  const size_t ldA32 = (size_t)32 * lda;
  const size_t ldB32 = (size_t)32 * ldb;

  bf16* ldsA = As + w * 512;
  bf16* ldsB = Bs + w * 512;

  const int wm = (w >> 1) * 64, wn = (w & 1) * 64;
  const int lr = l & 15;
  const int lc = l >> 4;

  f32x4 acc[4][4];
#pragma unroll
  for (int i = 0; i < 4; ++i)
#pragma unroll
    for (int j = 0; j < 4; ++j) { f32x4 zv = {0.f, 0.f, 0.f, 0.f}; acc[i][j] = zv; }

  const int nkt = K >> 6;
  for (int kt = 0; kt < nkt; ++kt) {
    __syncthreads();
#pragma unroll
    for (int j = 0; j < 4; ++j) {
      async_load16(pA + j * ldA32, ldsA + j * 2048);
      async_load16(pB + j * ldB32, ldsB + j * 2048);
    }
    pA += 64; pB += 64;
    __syncthreads();
#pragma unroll
    for (int ks = 0; ks < 2; ++ks) {
      bf16x8 af[4], bv[4];
#pragma unroll
      for (int i = 0; i < 4; ++i) {
        const int row = wm + i * 16 + lr;
        const int p = (ks * 4 + lc) ^ ((row >> 1) & 7);
        af[i] = *(const bf16x8*)&As[row * 64 + p * 8];
      }
#pragma unroll
      for (int i = 0; i < 4; ++i) {
        const int row = wn + i * 16 + lr;
        const int p = (ks * 4 + lc) ^ ((row >> 1) & 7);
        bv[i] = *(const bf16x8*)&Bs[row * 64 + p * 8];
      }
#pragma unroll
      for (int mi = 0; mi < 4; ++mi)
#pragma unroll
        for (int ni = 0; ni < 4; ++ni)
          acc[mi][ni] = __builtin_amdgcn_mfma_f32_16x16x32_bf16(af[mi], bv[ni], acc[mi][ni], 0, 0, 0);
    }
  }

  float* cs = Smem + w * 2304;
  const size_t offC = (size_t)zb * bCb + (size_t)zh * bCh;
  const int rq = (l >> 4) * 4;

#pragma unroll
  for (int p = 0; p < 2; ++p) {
    __syncthreads();
#pragma unroll
    for (int ni2 = 0; ni2 < 2; ++ni2) {
      const int ni = 2 * p + ni2;
      const int cl = ni2 * 16 + lr;
#pragma unroll
      for (int mi = 0; mi < 4; ++mi)
#pragma unroll
        for (int r = 0; r < 4; ++r)
          cs[(mi * 16 + rq + r) * 36 + cl] = acc[mi][ni][r];
    }
    __syncthreads();
    if (outB) {
      const int rl0 = l >> 2, c8 = (l & 3) * 8;
#pragma unroll
      for (int sub = 0; sub < 4; ++sub) {
        const int rl = sub * 16 + rl0;
        const int rowg = m0 + wm + rl;
        const int colg = n0 + wn + p * 32 + c8;
        float vv[8];
        *(f32x4*)&vv[0] = *(const f32x4*)&cs[rl * 36 + c8];
        *(f32x4*)&vv[4] = *(const f32x4*)&cs[rl * 36 + c8 + 4];
#pragma unroll
        for (int j = 0; j < 8; ++j) vv[j] *= scale;
        if (bias) {
          const float4 b0 = *(const float4*)(bias + colg);
          const float4 b1 = *(const float4*)(bias + colg + 4);
          vv[0] += b0.x; vv[1] += b0.y; vv[2] += b0.z; vv[3] += b0.w;
          vv[4] += b1.x; vv[5] += b1.y; vv[6] += b1.z; vv[7] += b1.w;
        }
        if (res) {
          const float4 r0 = *(const float4*)(res + (size_t)rowg * ldr + colg);
          const float4 r1 = *(const float4*)(res + (size_t)rowg * ldr + colg + 4);
          vv[0] += r0.x; vv[1] += r0.y; vv[2] += r0.z; vv[3] += r0.w;
          vv[4] += r1.x; vv[5] += r1.y; vv[6] += r1.z; vv[7] += r1.w;
        }
        if (relu)
#pragma unroll
          for (int j = 0; j < 8; ++j) vv[j] = fmaxf(vv[j], 0.0f);
        union { bf16 h8[8]; float4 f; } u;
#pragma unroll
        for (int j = 0; j < 8; ++j) u.h8[j] = (bf16)vv[j];
        *(float4*)(outB + offC + (size_t)rowg * ldc + colg) = u.f;
      }
    } else {
      const int rl0 = l >> 3, c4 = (l & 7) * 4;
#pragma unroll
      for (int sub = 0; sub < 8; ++sub) {
        const int rl = sub * 8 + rl0;
        const int rowg = m0 + wm + rl;
        const int colg = n0 + wn + p * 32 + c4;
        float4 v = *(const float4*)&cs[rl * 36 + c4];
        v.x *= scale; v.y *= scale; v.z *= scale; v.w *= scale;
        *(float4*)(outF + offC + (size_t)rowg * ldc + colg) = v;
      }
    }
  }
}

// ---------------- fp8 MX GEMM: C = A @ Bt^T (A: MxK, Bt: NxK, both fp8 e4m3, row-major)
// 128x128 tile, BK=128, mfma_scale_f32_16x16x128_f8f6f4 with unit scales (0x7F e8m0).
// LDS tile rows are 128 B (= bank period) with the same XOR 16B-chunk swizzle as gemm_bt.
// Fragment: row=lane&15, k=(lane>>4)*32 (32 consecutive fp8 = 2x ds_read_b128).
// modes: 0 = fp8 out (v*scale); 1 = fp8 out exp(v*scale) [scores];
//        2 = fp8 out v*scale/rowdiv[z*SEQ+row] [attn@V, O*16]; 3 = fp32 partials (split-K).
// vmode: QKV only — col tiles n0>=8192 are V, written transposed as vT[(b*8+h)][e][s] fp8.
__global__ void gemm_f8(const unsigned char* __restrict__ A, const unsigned char* __restrict__ Bt,
                        float* __restrict__ outF, unsigned char* __restrict__ out8,
                        unsigned char* __restrict__ vTout, const float* __restrict__ rowdiv,
                        int lda, int ldb, int ldc, int K,
                        long long bAb, long long bAh, long long bBb, long long bBh,
                        long long bCb, long long bCh, int zdiv,
                        float scale, int mode, int vmode)
{
  __shared__ __attribute__((aligned(16))) float Smem[4 * 2304];  // 36864 B
  unsigned char* As = (unsigned char*)Smem;       // 128x128 fp8 = 16 KB
  unsigned char* Bs = As + 128 * 128;             // 16 KB

  const int t = threadIdx.x;
  const int w = t >> 6, l = t & 63;
  const int m0 = blockIdx.y * 128, n0 = blockIdx.x * 128;
  const int z = blockIdx.z;
  const int zb = z / zdiv, zh = z - zb * zdiv;

  const unsigned char* Ab = A + (size_t)zb * bAb + (size_t)zh * bAh;
  const unsigned char* Bb = Bt + (size_t)zb * bBb + (size_t)zh * bBh;

  // staging: call j: row = j*32+(t>>3), phys chunk t&7 holds global chunk (t&7)^((t>>4)&7)
  const int srow = t >> 3;                              // 0..31
  const int gch  = ((t & 7) ^ ((t >> 4) & 7)) * 16;     // byte offset of 16B chunk
  const unsigned char* pA = Ab + (size_t)(m0 + srow) * lda + gch;
  const unsigned char* pB = Bb + (size_t)(n0 + srow) * ldb + gch;
  const size_t ldA32 = (size_t)32 * lda;
  const size_t ldB32 = (size_t)32 * ldb;

  unsigned char* ldsA = As + w * 1024;   // + j*4096 per call
  unsigned char* ldsB = Bs + w * 1024;

  const int wm = (w >> 1) * 64, wn = (w & 1) * 64;
  const int lr = l & 15;                 // row within 16
  const int lg = l >> 4;                 // 32-byte k-group (0..3)

  f32x4 acc[4][4];
#pragma unroll
  for (int i = 0; i < 4; ++i)
#pragma unroll
    for (int j = 0; j < 4; ++j) { f32x4 zv = {0.f, 0.f, 0.f, 0.f}; acc[i][j] = zv; }

  const int nkt = K >> 7;                // BK=128
  for (int kt = 0; kt < nkt; ++kt) {
    __syncthreads();
#pragma unroll
    for (int j = 0; j < 4; ++j) {
      async_load16(pA + j * ldA32, ldsA + j * 4096);
      async_load16(pB + j * ldB32, ldsB + j * 4096);
    }
    pA += 128; pB += 128;
    __syncthreads();
    i32x8 bv[4];
#pragma unroll
    for (int i = 0; i < 4; ++i) {
      const int row = wn + i * 16 + lr;
      const int s = (row >> 1) & 7;
      const int c0 = (2 * lg) ^ s, c1 = (2 * lg + 1) ^ s;
      const int4 lo = *(const int4*)&Bs[row * 128 + c0 * 16];
      const int4 hi = *(const int4*)&Bs[row * 128 + c1 * 16];
      i32x8 v = {lo.x, lo.y, lo.z, lo.w, hi.x, hi.y, hi.z, hi.w};
      bv[i] = v;
    }
#pragma unroll
    for (int mi = 0; mi < 4; ++mi) {
      const int row = wm + mi * 16 + lr;
      const int s = (row >> 1) & 7;
      const int c0 = (2 * lg) ^ s, c1 = (2 * lg + 1) ^ s;
      const int4 lo = *(const int4*)&As[row * 128 + c0 * 16];
      const int4 hi = *(const int4*)&As[row * 128 + c1 * 16];
      i32x8 af = {lo.x, lo.y, lo.z, lo.w, hi.x, hi.y, hi.z, hi.w};
#pragma unroll
      for (int ni = 0; ni < 4; ++ni)
        acc[mi][ni] = __builtin_amdgcn_mfma_scale_f32_16x16x128_f8f6f4(
            af, bv[ni], acc[mi][ni], 0, 0, 0, 0x7f7f7f7f, 0, 0x7f7f7f7f);
    }
  }

  // ---- LDS-staged epilogue (C/D 16x16 layout: col=lane&15, row=(lane>>4)*4+r) ----
  float* cs = Smem + w * 2304;
  const size_t offC = (size_t)zb * bCb + (size_t)zh * bCh;
  const int rq = (l >> 4) * 4;

  if (vmode && n0 >= 8192) {
    // V-projection tiles: store transposed into vT[(b*8+h)][e][s], fp8
    const int b8 = (m0 + wm) >> 10;
    const int s0 = (m0 + wm) & 1023;
#pragma unroll
    for (int ph = 0; ph < 2; ++ph) {
      __syncthreads();
#pragma unroll
      for (int ni2 = 0; ni2 < 2; ++ni2) {
        const int ni = 2 * ph + ni2;
        const int cl = ni2 * 16 + lr;
#pragma unroll
        for (int mi = 0; mi < 4; ++mi)
#pragma unroll
          for (int r = 0; r < 4; ++r)
            cs[cl * 68 + mi * 16 + rq + r] = acc[mi][ni][r];  // transposed: [col][row]
      }
      __syncthreads();
      const int c = l & 31, half = l >> 5;
      int e = (n0 - 8192) + wn + ph * 32 + c;
      const int h = e >> 9; e &= 511;
      unsigned char* dst = vTout + (((size_t)(b8 * 8 + h) * 512 + e) << 10) + s0 + half * 32;
      float vv[32];
#pragma unroll
      for (int j = 0; j < 8; ++j)
        *(f32x4*)&vv[4 * j] = *(const f32x4*)&cs[c * 68 + half * 32 + 4 * j];
#pragma unroll
      for (int j = 0; j < 32; ++j) vv[j] *= scale;
      *(int4*)dst        = pack16_fp8(&vv[0]);
      *(int4*)(dst + 16) = pack16_fp8(&vv[16]);
    }
    return;
  }

#pragma unroll
  for (int ph = 0; ph < 2; ++ph) {
    __syncthreads();
#pragma unroll
    for (int ni2 = 0; ni2 < 2; ++ni2) {
      const int ni = 2 * ph + ni2;
      const int cl = ni2 * 16 + lr;
#pragma unroll
      for (int mi = 0; mi < 4; ++mi)
#pragma unroll
        for (int r = 0; r < 4; ++r)
          cs[(mi * 16 + rq + r) * 36 + cl] = acc[mi][ni][r];
    }
    __syncthreads();
    if (mode == 3) {
      // fp32 split-K partials
      const int rl0 = l >> 3, c4 = (l & 7) * 4;
#pragma unroll
      for (int sub = 0; sub < 8; ++sub) {
        const int rl = sub * 8 + rl0;
        const int rowg = m0 + wm + rl;
        const int colg = n0 + wn + ph * 32 + c4;
        float4 v = *(const float4*)&cs[rl * 36 + c4];
        v.x *= scale; v.y *= scale; v.z *= scale; v.w *= scale;
        *(float4*)(outF + offC + (size_t)rowg * ldc + colg) = v;
      }
    } else {
      // fp8 output: lane packs 16 consecutive cols of one row -> 16B store
      const int rl0 = l >> 1, c16 = (l & 1) * 16;
#pragma unroll
      for (int sub = 0; sub < 2; ++sub) {
        const int rl = sub * 32 + rl0;
        const int rowg = m0 + wm + rl;
        const int colg = n0 + wn + ph * 32 + c16;
        float vv[16];
#pragma unroll
        for (int j2 = 0; j2 < 4; ++j2)
          *(f32x4*)&vv[4 * j2] = *(const f32x4*)&cs[rl * 36 + c16 + 4 * j2];
        if (mode == 1) {
#pragma unroll
          for (int j = 0; j < 16; ++j) vv[j] = __expf(vv[j] * scale);
        } else if (mode == 2) {
          const float d = scale / rowdiv[(size_t)z * SEQ + rowg];
#pragma unroll
          for (int j = 0; j < 16; ++j) vv[j] *= d;
        } else {
#pragma unroll
          for (int j = 0; j < 16; ++j) vv[j] *= scale;
        }
        *(int4*)(out8 + offC + (size_t)rowg * ldc + colg) = pack16_fp8(vv);
      }
    }
  }
}

// ---------------- cast x (fp32 -> fp8 e4m3), 16 elems/thread ----------------
__global__ void cast_x_f8(const float* __restrict__ in, unsigned char* __restrict__ out, int n16) {
  int i = blockIdx.x * 256 + threadIdx.x;
  if (i >= n16) return;
  const float4* p = (const float4*)in + (size_t)i * 4;
  float vv[16];
  *(f32x4*)&vv[0]  = *(const f32x4*)&p[0];
  *(f32x4*)&vv[4]  = *(const f32x4*)&p[1];
  *(f32x4*)&vv[8]  = *(const f32x4*)&p[2];
  *(f32x4*)&vv[12] = *(const f32x4*)&p[3];
  ((int4*)out)[i] = pack16_fp8(vv);
}

// ---------------- batched weight transpose+cast: fp32 [K][N] -> fp8/bf16 [N][K] ----------------
struct WTList {
  const float* in[6];
  void* out[6];
  float scale[6];
  int isf8[6];
  int K[6], N[6];
  int start[7];   // prefix sums of block counts
};
__global__ void transpose_cast_all(WTList L) {
  __shared__ float tile[32][33];
  int bid = blockIdx.x;
  int i = 0;
  while (bid >= L.start[i + 1]) ++i;
  int rel = bid - L.start[i];
  const int N = L.N[i], K = L.K[i];
  const int nx = N >> 5;
  const int n0 = (rel % nx) * 32, k0 = (rel / nx) * 32;
  const float* in = L.in[i];
  const float sc = L.scale[i];
  int tx = threadIdx.x, ty = threadIdx.y;
#pragma unroll
  for (int j = 0; j < 32; j += 8)
    tile[ty + j][tx] = in[(size_t)(k0 + ty + j) * N + n0 + tx];
  __syncthreads();
  if (L.isf8[i]) {
    unsigned char* out = (unsigned char*)L.out[i];
#pragma unroll
    for (int j = 0; j < 32; j += 8)
      out[(size_t)(n0 + ty + j) * K + k0 + tx] =
          (unsigned char)(pk_fp8_lo(tile[tx][ty + j] * sc, 0.f, 0) & 0xff);
  } else {
    bf16* out = (bf16*)L.out[i];
#pragma unroll
    for (int j = 0; j < 32; j += 8)
      out[(size_t)(n0 + ty + j) * K + k0 + tx] = (bf16)(tile[tx][ty + j] * sc);
  }
}

// ---------------- row sums of exp-scores (fp8), one wave per row of 1024 ----------------
__global__ void rowsum_f8(const unsigned char* __restrict__ e, float* __restrict__ lsum) {
  int ln = threadIdx.x & 63, w = threadIdx.x >> 6;
  size_t row = (size_t)blockIdx.x * 4 + w;
  const int4 v = ((const int4*)(e + row * SEQ))[ln];
  float s = 0.0f;
  s += F8DEC(v.x, 0) + F8DEC(v.x, 1) + F8DEC(v.x, 2) + F8DEC(v.x, 3);
  s += F8DEC(v.y, 0) + F8DEC(v.y, 1) + F8DEC(v.y, 2) + F8DEC(v.y, 3);
  s += F8DEC(v.z, 0) + F8DEC(v.z, 1) + F8DEC(v.z, 2) + F8DEC(v.z, 3);
  s += F8DEC(v.w, 0) + F8DEC(v.w, 1) + F8DEC(v.w, 2) + F8DEC(v.w, 3);
#pragma unroll
  for (int d = 1; d < 64; d <<= 1) s += __shfl_xor(s, d);
  if (ln == 0) lsum[row] = s;
}

// ---------------- split-K reduce + residual + bias + layernorm, one wave per row ----------------
__global__ void reduce_ln(const float* __restrict__ parts, int ns,
                          const float* __restrict__ res, const float* __restrict__ bias,
                          const float* __restrict__ gw, const float* __restrict__ bw,
                          float* __restrict__ outF, bf16* __restrict__ outB) {
  int l = threadIdx.x & 63, w = threadIdx.x >> 6;
  int row = blockIdx.x * 4 + w;
  const long long pstr = (long long)MTOK * EBD;
  float4 a = {0.f, 0.f, 0.f, 0.f}, b = {0.f, 0.f, 0.f, 0.f};
  for (int s = 0; s < ns; ++s) {
    const float4* p = (const float4*)(parts + s * pstr + (size_t)row * EBD);
    float4 pa = p[l], pb = p[l + 64];
    a.x += pa.x; a.y += pa.y; a.z += pa.z; a.w += pa.w;
    b.x += pb.x; b.y += pb.y; b.z += pb.z; b.w += pb.w;
  }
  {
    const float4* p = (const float4*)(res + (size_t)row * EBD);
    float4 pa = p[l], pb = p[l + 64];
    a.x += pa.x; a.y += pa.y; a.z += pa.z; a.w += pa.w;
    b.x += pb.x; b.y += pb.y; b.z += pb.z; b.w += pb.w;
  }
  if (bias) {
    const float4* p = (const float4*)bias;
    float4 pa = p[l], pb = p[l + 64];
    a.x += pa.x; a.y += pa.y; a.z += pa.z; a.w += pa.w;
    b.x += pb.x; b.y += pb.y; b.z += pb.z; b.w += pb.w;
  }
  float s = a.x + a.y + a.z + a.w + b.x + b.y + b.z + b.w;
  float q = a.x * a.x + a.y * a.y + a.z * a.z + a.w * a.w
          + b.x * b.x + b.y * b.y + b.z * b.z + b.w * b.w;
#pragma unroll
  for (int d = 1; d < 64; d <<= 1) { s += __shfl_xor(s, d); q += __shfl_xor(q, d); }
  float mu = s * (1.0f / EBD);
  float var = q * (1.0f / EBD) - mu * mu;
  float rs = rsqrtf(var + 1e-5f);
  const float4* g4 = (const float4*)gw;
  const float4* b4 = (const float4*)bw;
  float4 ga = g4[l], gb = g4[l + 64], ba = b4[l], bb = b4[l + 64];
  float4 o0, o1;
  o0.x = (a.x - mu) * rs * ga.x + ba.x;
  o0.y = (a.y - mu) * rs * ga.y + ba.y;
  o0.z = (a.z - mu) * rs * ga.z + ba.z;
  o0.w = (a.w - mu) * rs * ga.w + ba.w;
  o1.x = (b.x - mu) * rs * gb.x + bb.x;
  o1.y = (b.y - mu) * rs * gb.y + bb.y;
  o1.z = (b.z - mu) * rs * gb.z + bb.z;
  o1.w = (b.w - mu) * rs * gb.w + bb.w;
  if (outF) {
    float4* q4 = (float4*)(outF + (size_t)row * EBD);
    q4[l] = o0; q4[l + 64] = o1;
  }
  if (outB) {
    union { bf16 h[4]; float2 f; } u0, u1;
    u0.h[0] = (bf16)o0.x; u0.h[1] = (bf16)o0.y; u0.h[2] = (bf16)o0.z; u0.h[3] = (bf16)o0.w;
    u1.h[0] = (bf16)o1.x; u1.h[1] = (bf16)o1.y; u1.h[2] = (bf16)o1.z; u1.h[3] = (bf16)o1.w;
    float2* r2 = (float2*)(outB + (size_t)row * EBD);
    r2[l] = u0.f; r2[l + 64] = u1.f;
  }
}

// ---------------- host-side orchestration ----------------
extern "C" void kernel_launch(void* const* d_in, const int* in_sizes, int n_in,
                              void* d_out, int out_size, void* d_ws, size_t ws_size,
                              hipStream_t stream) {
  const float* x  = (const float*)d_in[0];
  const float* Wq = (const float*)d_in[1];
  const float* Wk = (const float*)d_in[2];
  const float* Wv = (const float*)d_in[3];
  const float* Wo = (const float*)d_in[4];
  const float* g1 = (const float*)d_in[5];
  const float* b1 = (const float*)d_in[6];
  const float* g2 = (const float*)d_in[7];
  const float* b2 = (const float*)d_in[8];
  const float* W1 = (const float*)d_in[9];
  const float* c1 = (const float*)d_in[10];
  const float* W2 = (const float*)d_in[11];
  const float* c2 = (const float*)d_in[12];
  float* out = (float*)d_out;

  char* p = (char*)d_ws;
  auto take = [&](size_t bytes) { char* r = p; p += (bytes + 255) & ~(size_t)255; return r; };
  unsigned char* xb8    = (unsigned char*)take((size_t)MTOK * EBD);        //  2 MB
  unsigned char* qk8    = (unsigned char*)take((size_t)MTOK * 2 * HE);     // 32 MB [4096][8192]
  unsigned char* vT8    = (unsigned char*)take((size_t)32 * EBD * SEQ);    // 16 MB [(b,h)][e][s]
  unsigned char* sc8    = (unsigned char*)take((size_t)32 * SEQ * SEQ);    // 32 MB exp-scores (fp32 partials overlay later)
  float*         lsum   = (float*)        take((size_t)32 * SEQ * 4);      // 128 KB row sums
  unsigned char* ao8    = (unsigned char*)take((size_t)MTOK * HE);         // 16 MB O*16
  float*         nF     = (float*)        take((size_t)MTOK * EBD * 4);    //  8 MB
  bf16*          nB     = (bf16*)         take((size_t)MTOK * EBD * 2);    //  4 MB
  bf16*          hb     = (bf16*)         take((size_t)MTOK * FFD * 2);    // 16 MB
  unsigned char* Wqkv8T = (unsigned char*)take((size_t)3 * HE * EBD);      //  6 MB [12288][512]
  unsigned char* Wo8T   = (unsigned char*)take((size_t)EBD * HE);          //  2 MB [512][4096]
  bf16*          W1T    = (bf16*)         take((size_t)FFD * EBD * 2);     //  2 MB
  bf16*          W2T    = (bf16*)         take((size_t)EBD * FFD * 2);     //  2 MB   total ~138 MB
  float* parts = (float*)sc8;   // 32 MB fp32 split-K partials (sc8 dead after attn@V)

  auto gemmf8 = [&](const unsigned char* A, const unsigned char* Bt, float* oF,
                    unsigned char* o8, unsigned char* vTo, const float* rdiv,
                    int Mm, int Nn, int Kk, int lda_, int ldb_, int ldc_,
                    long long bAb, long long bAh, long long bBb, long long bBh,
                    long long bCb, long long bCh, int zdiv_, int batch,
                    float sc_, int mode_, int vmode_) {
    dim3 g(Nn / 128, Mm / 128, batch);
    gemm_f8<<<g, dim3(256), 0, stream>>>(A, Bt, oF, o8, vTo, rdiv, lda_, ldb_, ldc_, Kk,
        bAb, bAh, bBb, bBh, bCb, bCh, zdiv_, sc_, mode_, vmode_);
  };
  auto gemmbf = [&](const bf16* A, const bf16* Bt, float* oF, bf16* oB,
                    const float* bias, const float* res,
                    int Mm, int Nn, int Kk, int lda_, int ldb_, int ldc_, int ldr_,
                    long long bAh, long long bBh, long long bCh, int batch,
                    float sc_, int relu_) {
    dim3 g(Nn / 128, Mm / 128, batch);
    gemm_bt<<<g, dim3(256), 0, stream>>>(A, Bt, oF, oB, bias, res,
        lda_, ldb_, ldc_, ldr_, Kk, 0, bAh, 0, bBh, 0, bCh, 64, sc_, relu_);
  };

  // --- preprocessing: x -> fp8; weights: Wq/Wk/Wv x8 fp8, Wo x16 fp8, W1/W2 bf16 ---
  cast_x_f8<<<dim3(MTOK * EBD / 16 / 256), dim3(256), 0, stream>>>(x, xb8, MTOK * EBD / 16);
  {
    WTList L;
    const float* ins[6] = {Wq, Wk, Wv, Wo, W1, W2};
    void* outs[6] = {Wqkv8T, Wqkv8T + (size_t)HE * EBD, Wqkv8T + (size_t)2 * HE * EBD,
                     Wo8T, W1T, W2T};
    float scs[6] = {8.f, 8.f, 8.f, 16.f, 1.f, 1.f};
    int f8s[6] = {1, 1, 1, 1, 0, 0};
    int Ks[6] = {EBD, EBD, EBD, HE, EBD, FFD};
    int Ns[6] = {HE, HE, HE, EBD, FFD, EBD};
    int acc = 0;
    for (int i = 0; i < 6; ++i) {
      L.in[i] = ins[i]; L.out[i] = outs[i]; L.scale[i] = scs[i]; L.isf8[i] = f8s[i];
      L.K[i] = Ks[i]; L.N[i] = Ns[i]; L.start[i] = acc;
      acc += (Ks[i] / 32) * (Ns[i] / 32);
    }
    L.start[6] = acc;
    transpose_cast_all<<<dim3(acc), dim3(32, 8), 0, stream>>>(L);
  }

  // --- fused QKV (fp8): q,k -> qk8 [4096][8192]; V -> vT8 transposed; scale 1/8 ---
  gemmf8(xb8, Wqkv8T, nullptr, qk8, vT8, nullptr, MTOK, 3 * HE, EBD,
         EBD, EBD, 2 * HE, 0, 0, 0, 0, 0, 0, 64, 1, 0.125f, 0, 1);

  // --- exp-scores = exp(q.k / sqrt(E)) fp8, batched over 32 (b,h) (no max-sub: |score|<~2) ---
  const float qs = 0.04419417382415922f;  // 1/sqrt(512)
  gemmf8(qk8, qk8 + HE, nullptr, sc8, nullptr, nullptr, SEQ, SEQ, EBD,
         2 * HE, 2 * HE, SEQ,
         (long long)SEQ * 2 * HE, EBD, (long long)SEQ * 2 * HE, EBD,
         (long long)8 * SEQ * SEQ, (long long)SEQ * SEQ, 8, 32, qs, 1, 0);

  rowsum_f8<<<dim3(32 * SEQ / 4), dim3(256), 0, stream>>>(sc8, lsum);

  // --- O = (exp-scores @ v) * 16 / l, fp8 out into ao8 [token][h*512+e] ---
  gemmf8(sc8, vT8, nullptr, ao8, nullptr, lsum, SEQ, EBD, SEQ,
         SEQ, SEQ, HE,
         (long long)8 * SEQ * SEQ, (long long)SEQ * SEQ,
         (long long)8 * EBD * SEQ, (long long)EBD * SEQ,
         (long long)SEQ * HE, (long long)EBD, 8, 32, 16.0f, 2, 0);

  // --- O16 @ Wo16^T, split-K x4 (K=4096) -> fp32 partials (scale 1/256); reduce + x + LN1 ---
  gemmf8(ao8, Wo8T, parts, nullptr, nullptr, nullptr, MTOK, EBD, 1024,
         HE, HE, EBD, 0, 1024, 0, 1024, 0, (long long)MTOK * EBD, 64, 4,
         1.0f / 256.0f, 3, 0);
  reduce_ln<<<dim3(MTOK / 4), dim3(256), 0, stream>>>(parts, 4, x, nullptr, g1, b1, nF, nB);

  // --- FF (bf16): h = relu(n @ W1 + c1); ff = h @ W2 split-K x4; reduce + c2 + n + LN2 ---
  gemmbf(nB, W1T, nullptr, hb, c1, nullptr, MTOK, FFD, EBD,
         EBD, EBD, FFD, 0, 0, 0, 0, 1, 1.0f, 1);
  gemmbf(hb, W2T, parts, nullptr, nullptr, nullptr, MTOK, EBD, 512,
         FFD, FFD, EBD, 0, 512, 512, (long long)MTOK * EBD, 4, 1.0f, 0);
  reduce_ln<<<dim3(MTOK / 4), dim3(256), 0, stream>>>(parts, 4, nF, c2, g2, b2, out, nullptr);
}

// Round 7
// 278.916 us; speedup vs baseline: 2.1186x; 1.0645x over previous
//
#include <hip/hip_runtime.h>
#include <hip/hip_fp8.h>

// ---------------- constants for this problem ----------------
#define EBD   512      // embed size (= head dim here)
#define NHEAD 8
#define BSZ   4
#define SEQ   1024
#define MTOK  4096     // B*S tokens
#define HE    4096     // H*E
#define FFD   2048     // 4*E

typedef __bf16 bf16;
typedef __attribute__((ext_vector_type(4))) float  f32x4;
typedef __attribute__((ext_vector_type(8))) int    i32x8;

// async global->LDS, 16B per lane; LDS dest must be wave-uniform base + lane*16
__device__ __forceinline__ void async_load16(const void* g, void* l) {
  __builtin_amdgcn_global_load_lds(
      (const __attribute__((address_space(1))) void*)g,
      (__attribute__((address_space(3))) void*)l, 16, 0, 0);
}

// ---------------- fp8 e4m3 (OCP) convert helpers ----------------
#if __has_builtin(__builtin_amdgcn_cvt_pk_fp8_f32)
__device__ __forceinline__ int pk_fp8_lo(float a, float b, int old) {
  return __builtin_amdgcn_cvt_pk_fp8_f32(a, b, old, false);
}
__device__ __forceinline__ int pk_fp8_hi(float a, float b, int old) {
  return __builtin_amdgcn_cvt_pk_fp8_f32(a, b, old, true);
}
#else
__device__ __forceinline__ int pk_fp8_lo(float a, float b, int old) {
  __hip_fp8_e4m3 fa(a), fb(b);
  int w = (int)fa.__x | ((int)fb.__x << 8);
  return (old & ~0xffff) | w;
}
__device__ __forceinline__ int pk_fp8_hi(float a, float b, int old) {
  __hip_fp8_e4m3 fa(a), fb(b);
  int w = (int)fa.__x | ((int)fb.__x << 8);
  return (old & 0xffff) | (w << 16);
}
#endif

__device__ __forceinline__ int4 pack16_fp8(const float* v) {
  int4 r;
  r.x = pk_fp8_hi(v[2],  v[3],  pk_fp8_lo(v[0],  v[1],  0));
  r.y = pk_fp8_hi(v[6],  v[7],  pk_fp8_lo(v[4],  v[5],  0));
  r.z = pk_fp8_hi(v[10], v[11], pk_fp8_lo(v[8],  v[9],  0));
  r.w = pk_fp8_hi(v[14], v[15], pk_fp8_lo(v[12], v[13], 0));
  return r;
}

// ---------------- fp8 MX GEMM: C = A @ Bt^T (A: MxK, Bt: NxK, both fp8 e4m3, row-major)
// 128x128 tile, BK=128, mfma_scale_f32_16x16x128_f8f6f4 with unit scales (0x7F e8m0).
// LDS rows = 128 B (bank period) with XOR 16B-chunk swizzle (verified r5/r6).
// Epilogue (LDS-staged, coalesced):
//   v = acc*scale + bias[col]; relu optional; then per mode:
//   0 = fp8 out;  1 = fp8 out exp(v) + atomic row-sum into lsum [scores];
//   2 = fp8 out v/rowdiv[z*SEQ+row] [attn@V];  3 = fp32 partial stores (split-K).
// vmode: QKV only — col tiles n0>=8192 are V, written transposed as vT[(b*8+h)][e][s] fp8.
__global__ void gemm_f8(const unsigned char* __restrict__ A, const unsigned char* __restrict__ Bt,
                        float* __restrict__ outF, unsigned char* __restrict__ out8,
                        unsigned char* __restrict__ vTout, const float* __restrict__ rowdiv,
                        const float* __restrict__ bias, float* __restrict__ lsum,
                        int lda, int ldb, int ldc, int K,
                        long long bAb, long long bAh, long long bBb, long long bBh,
                        long long bCb, long long bCh, int zdiv,
                        float scale, int mode, int relu, int vmode)
{
  __shared__ __attribute__((aligned(16))) float Smem[4 * 2304];  // 36864 B
  unsigned char* As = (unsigned char*)Smem;       // 128x128 fp8 = 16 KB
  unsigned char* Bs = As + 128 * 128;             // 16 KB

  const int t = threadIdx.x;
  const int w = t >> 6, l = t & 63;
  const int m0 = blockIdx.y * 128, n0 = blockIdx.x * 128;
  const int z = blockIdx.z;
  const int zb = z / zdiv, zh = z - zb * zdiv;

  const unsigned char* Ab = A + (size_t)zb * bAb + (size_t)zh * bAh;
  const unsigned char* Bb = Bt + (size_t)zb * bBb + (size_t)zh * bBh;

  // staging: call j: row = j*32+(t>>3), phys chunk t&7 holds global chunk (t&7)^((t>>4)&7)
  const int srow = t >> 3;                              // 0..31
  const int gch  = ((t & 7) ^ ((t >> 4) & 7)) * 16;     // byte offset of 16B chunk
  const unsigned char* pA = Ab + (size_t)(m0 + srow) * lda + gch;
  const unsigned char* pB = Bb + (size_t)(n0 + srow) * ldb + gch;
  const size_t ldA32 = (size_t)32 * lda;
  const size_t ldB32 = (size_t)32 * ldb;

  unsigned char* ldsA = As + w * 1024;   // + j*4096 per call
  unsigned char* ldsB = Bs + w * 1024;

  const int wm = (w >> 1) * 64, wn = (w & 1) * 64;
  const int lr = l & 15;                 // row within 16
  const int lg = l >> 4;                 // 32-byte k-group (0..3)

  f32x4 acc[4][4];
#pragma unroll
  for (int i = 0; i < 4; ++i)
#pragma unroll
    for (int j = 0; j < 4; ++j) { f32x4 zv = {0.f, 0.f, 0.f, 0.f}; acc[i][j] = zv; }

  const int nkt = K >> 7;                // BK=128
  for (int kt = 0; kt < nkt; ++kt) {
    __syncthreads();
#pragma unroll
    for (int j = 0; j < 4; ++j) {
      async_load16(pA + j * ldA32, ldsA + j * 4096);
      async_load16(pB + j * ldB32, ldsB + j * 4096);
    }
    pA += 128; pB += 128;
    __syncthreads();
    i32x8 bv[4];
#pragma unroll
    for (int i = 0; i < 4; ++i) {
      const int row = wn + i * 16 + lr;
      const int s = (row >> 1) & 7;
      const int c0 = (2 * lg) ^ s, c1 = (2 * lg + 1) ^ s;
      const int4 lo = *(const int4*)&Bs[row * 128 + c0 * 16];
      const int4 hi = *(const int4*)&Bs[row * 128 + c1 * 16];
      i32x8 v = {lo.x, lo.y, lo.z, lo.w, hi.x, hi.y, hi.z, hi.w};
      bv[i] = v;
    }
#pragma unroll
    for (int mi = 0; mi < 4; ++mi) {
      const int row = wm + mi * 16 + lr;
      const int s = (row >> 1) & 7;
      const int c0 = (2 * lg) ^ s, c1 = (2 * lg + 1) ^ s;
      const int4 lo = *(const int4*)&As[row * 128 + c0 * 16];
      const int4 hi = *(const int4*)&As[row * 128 + c1 * 16];
      i32x8 af = {lo.x, lo.y, lo.z, lo.w, hi.x, hi.y, hi.z, hi.w};
#pragma unroll
      for (int ni = 0; ni < 4; ++ni)
        acc[mi][ni] = __builtin_amdgcn_mfma_scale_f32_16x16x128_f8f6f4(
            af, bv[ni], acc[mi][ni], 0, 0, 0, 0x7f7f7f7f, 0, 0x7f7f7f7f);
    }
  }

  // ---- LDS-staged epilogue (C/D 16x16 layout: col=lane&15, row=(lane>>4)*4+r) ----
  float* cs = Smem + w * 2304;
  const size_t offC = (size_t)zb * bCb + (size_t)zh * bCh;
  const int rq = (l >> 4) * 4;

  if (vmode && n0 >= 8192) {
    // V-projection tiles: store transposed into vT[(b*8+h)][e][s], fp8
    const int b8 = (m0 + wm) >> 10;
    const int s0 = (m0 + wm) & 1023;
#pragma unroll
    for (int ph = 0; ph < 2; ++ph) {
      __syncthreads();
#pragma unroll
      for (int ni2 = 0; ni2 < 2; ++ni2) {
        const int ni = 2 * ph + ni2;
        const int cl = ni2 * 16 + lr;
#pragma unroll
        for (int mi = 0; mi < 4; ++mi)
#pragma unroll
          for (int r = 0; r < 4; ++r)
            cs[cl * 68 + mi * 16 + rq + r] = acc[mi][ni][r];  // transposed: [col][row]
      }
      __syncthreads();
      const int c = l & 31, half = l >> 5;
      int e = (n0 - 8192) + wn + ph * 32 + c;
      const int h = e >> 9; e &= 511;
      unsigned char* dst = vTout + (((size_t)(b8 * 8 + h) * 512 + e) << 10) + s0 + half * 32;
      float vv[32];
#pragma unroll
      for (int j = 0; j < 8; ++j)
        *(f32x4*)&vv[4 * j] = *(const f32x4*)&cs[c * 68 + half * 32 + 4 * j];
#pragma unroll
      for (int j = 0; j < 32; ++j) vv[j] *= scale;
      *(int4*)dst        = pack16_fp8(&vv[0]);
      *(int4*)(dst + 16) = pack16_fp8(&vv[16]);
    }
    return;
  }

  const int rl0 = l >> 1, c16 = (l & 1) * 16;   // fp8-out lane map
  float rsum[2] = {0.f, 0.f};                   // mode-1 per-row partial sums

#pragma unroll
  for (int ph = 0; ph < 2; ++ph) {
    __syncthreads();
#pragma unroll
    for (int ni2 = 0; ni2 < 2; ++ni2) {
      const int ni = 2 * ph + ni2;
      const int cl = ni2 * 16 + lr;
#pragma unroll
      for (int mi = 0; mi < 4; ++mi)
#pragma unroll
        for (int r = 0; r < 4; ++r)
          cs[(mi * 16 + rq + r) * 36 + cl] = acc[mi][ni][r];
    }
    __syncthreads();
    if (mode == 3) {
      // fp32 split-K partials
      const int prl0 = l >> 3, c4 = (l & 7) * 4;
#pragma unroll
      for (int sub = 0; sub < 8; ++sub) {
        const int rl = sub * 8 + prl0;
        const int rowg = m0 + wm + rl;
        const int colg = n0 + wn + ph * 32 + c4;
        float4 v = *(const float4*)&cs[rl * 36 + c4];
        v.x *= scale; v.y *= scale; v.z *= scale; v.w *= scale;
        *(float4*)(outF + offC + (size_t)rowg * ldc + colg) = v;
      }
    } else {
      // fp8 output: lane packs 16 consecutive cols of one row -> 16B store
#pragma unroll
      for (int sub = 0; sub < 2; ++sub) {
        const int rl = sub * 32 + rl0;
        const int rowg = m0 + wm + rl;
        const int colg = n0 + wn + ph * 32 + c16;
        float vv[16];
#pragma unroll
        for (int j2 = 0; j2 < 4; ++j2)
          *(f32x4*)&vv[4 * j2] = *(const f32x4*)&cs[rl * 36 + c16 + 4 * j2];
#pragma unroll
        for (int j = 0; j < 16; ++j) vv[j] *= scale;
        if (bias) {
#pragma unroll
          for (int j2 = 0; j2 < 4; ++j2) {
            const float4 b0 = *(const float4*)(bias + colg + 4 * j2);
            vv[4 * j2] += b0.x; vv[4 * j2 + 1] += b0.y;
            vv[4 * j2 + 2] += b0.z; vv[4 * j2 + 3] += b0.w;
          }
        }
        if (relu)
#pragma unroll
          for (int j = 0; j < 16; ++j) vv[j] = fmaxf(vv[j], 0.0f);
        if (mode == 1) {
          float s = 0.0f;
#pragma unroll
          for (int j = 0; j < 16; ++j) { vv[j] = __expf(vv[j]); s += vv[j]; }
          rsum[sub] += s;
        } else if (mode == 2) {
          const float d = 1.0f / rowdiv[(size_t)z * SEQ + rowg];
#pragma unroll
          for (int j = 0; j < 16; ++j) vv[j] *= d;
        }
        *(int4*)(out8 + offC + (size_t)rowg * ldc + colg) = pack16_fp8(vv);
      }
    }
  }
  if (mode == 1 && lsum) {
    // lanes l and l^1 hold the same row; combine, one atomic per pair
#pragma unroll
    for (int sub = 0; sub < 2; ++sub) {
      float s = rsum[sub] + __shfl_xor(rsum[sub], 1);
      if (!(l & 1)) {
        const int rowg = m0 + wm + sub * 32 + rl0;
        atomicAdd(&lsum[(size_t)z * SEQ + rowg], s);
      }
    }
  }
}

// ---------------- cast x (fp32 -> fp8 e4m3), 16 elems/thread; last block zeroes lsum ----------------
__global__ void cast_x_f8(const float* __restrict__ in, unsigned char* __restrict__ out,
                          int n16, float* __restrict__ lsum) {
  int i = blockIdx.x * 256 + threadIdx.x;
  if (i >= n16) {
    if (blockIdx.x == (unsigned)(n16 / 256)) {   // the extra tail block
      float4 zv = {0.f, 0.f, 0.f, 0.f};
      float4* q = (float4*)lsum;                 // 32*SEQ floats = 8192 float4
#pragma unroll
      for (int j = 0; j < 32; ++j) q[threadIdx.x * 32 + j] = zv;
    }
    return;
  }
  const float4* p = (const float4*)in + (size_t)i * 4;
  float vv[16];
  *(f32x4*)&vv[0]  = *(const f32x4*)&p[0];
  *(f32x4*)&vv[4]  = *(const f32x4*)&p[1];
  *(f32x4*)&vv[8]  = *(const f32x4*)&p[2];
  *(f32x4*)&vv[12] = *(const f32x4*)&p[3];
  ((int4*)out)[i] = pack16_fp8(vv);
}

// ---------------- batched weight transpose+cast: fp32 [K][N] -> fp8 [N][K], 6 weights ----------------
struct WTList {
  const float* in[6];
  unsigned char* out[6];
  float scale[6];
  int K[6], N[6];
  int start[7];   // prefix sums of block counts
};
__global__ void transpose_cast_all(WTList L) {
  __shared__ float tile[32][33];
  int bid = blockIdx.x;
  int i = 0;
  while (bid >= L.start[i + 1]) ++i;
  int rel = bid - L.start[i];
  const int N = L.N[i], K = L.K[i];
  const int nx = N >> 5;
  const int n0 = (rel % nx) * 32, k0 = (rel / nx) * 32;
  const float* in = L.in[i];
  const float sc = L.scale[i];
  unsigned char* out = L.out[i];
  int tx = threadIdx.x, ty = threadIdx.y;
#pragma unroll
  for (int j = 0; j < 32; j += 8)
    tile[ty + j][tx] = in[(size_t)(k0 + ty + j) * N + n0 + tx];
  __syncthreads();
#pragma unroll
  for (int j = 0; j < 32; j += 8)
    out[(size_t)(n0 + ty + j) * K + k0 + tx] =
        (unsigned char)(pk_fp8_lo(tile[tx][ty + j] * sc, 0.f, 0) & 0xff);
}

// ---------------- split-K reduce + residual + bias + layernorm, one wave per row ----------------
__global__ void reduce_ln(const float* __restrict__ parts, int ns,
                          const float* __restrict__ res, const float* __restrict__ bias,
                          const float* __restrict__ gw, const float* __restrict__ bw,
                          float* __restrict__ outF, unsigned char* __restrict__ out8) {
  int l = threadIdx.x & 63, w = threadIdx.x >> 6;
  int row = blockIdx.x * 4 + w;
  const long long pstr = (long long)MTOK * EBD;
  float4 a = {0.f, 0.f, 0.f, 0.f}, b = {0.f, 0.f, 0.f, 0.f};
  for (int s = 0; s < ns; ++s) {
    const float4* p = (const float4*)(parts + s * pstr + (size_t)row * EBD);
    float4 pa = p[l], pb = p[l + 64];
    a.x += pa.x; a.y += pa.y; a.z += pa.z; a.w += pa.w;
    b.x += pb.x; b.y += pb.y; b.z += pb.z; b.w += pb.w;
  }
  {
    const float4* p = (const float4*)(res + (size_t)row * EBD);
    float4 pa = p[l], pb = p[l + 64];
    a.x += pa.x; a.y += pa.y; a.z += pa.z; a.w += pa.w;
    b.x += pb.x; b.y += pb.y; b.z += pb.z; b.w += pb.w;
  }
  if (bias) {
    const float4* p = (const float4*)bias;
    float4 pa = p[l], pb = p[l + 64];
    a.x += pa.x; a.y += pa.y; a.z += pa.z; a.w += pa.w;
    b.x += pb.x; b.y += pb.y; b.z += pb.z; b.w += pb.w;
  }
  float s = a.x + a.y + a.z + a.w + b.x + b.y + b.z + b.w;
  float q = a.x * a.x + a.y * a.y + a.z * a.z + a.w * a.w
          + b.x * b.x + b.y * b.y + b.z * b.z + b.w * b.w;
#pragma unroll
  for (int d = 1; d < 64; d <<= 1) { s += __shfl_xor(s, d); q += __shfl_xor(q, d); }
  float mu = s * (1.0f / EBD);
  float var = q * (1.0f / EBD) - mu * mu;
  float rs = rsqrtf(var + 1e-5f);
  const float4* g4 = (const float4*)gw;
  const float4* b4 = (const float4*)bw;
  float4 ga = g4[l], gb = g4[l + 64], ba = b4[l], bb = b4[l + 64];
  float4 o0, o1;
  o0.x = (a.x - mu) * rs * ga.x + ba.x;
  o0.y = (a.y - mu) * rs * ga.y + ba.y;
  o0.z = (a.z - mu) * rs * ga.z + ba.z;
  o0.w = (a.w - mu) * rs * ga.w + ba.w;
  o1.x = (b.x - mu) * rs * gb.x + bb.x;
  o1.y = (b.y - mu) * rs * gb.y + bb.y;
  o1.z = (b.z - mu) * rs * gb.z + bb.z;
  o1.w = (b.w - mu) * rs * gb.w + bb.w;
  if (outF) {
    float4* q4 = (float4*)(outF + (size_t)row * EBD);
    q4[l] = o0; q4[l + 64] = o1;
  }
  if (out8) {
    int* o = (int*)(out8 + (size_t)row * EBD);
    o[l]      = pk_fp8_hi(o0.z, o0.w, pk_fp8_lo(o0.x, o0.y, 0));
    o[l + 64] = pk_fp8_hi(o1.z, o1.w, pk_fp8_lo(o1.x, o1.y, 0));
  }
}

// ---------------- host-side orchestration ----------------
extern "C" void kernel_launch(void* const* d_in, const int* in_sizes, int n_in,
                              void* d_out, int out_size, void* d_ws, size_t ws_size,
                              hipStream_t stream) {
  const float* x  = (const float*)d_in[0];
  const float* Wq = (const float*)d_in[1];
  const float* Wk = (const float*)d_in[2];
  const float* Wv = (const float*)d_in[3];
  const float* Wo = (const float*)d_in[4];
  const float* g1 = (const float*)d_in[5];
  const float* b1 = (const float*)d_in[6];
  const float* g2 = (const float*)d_in[7];
  const float* b2 = (const float*)d_in[8];
  const float* W1 = (const float*)d_in[9];
  const float* c1 = (const float*)d_in[10];
  const float* W2 = (const float*)d_in[11];
  const float* c2 = (const float*)d_in[12];
  float* out = (float*)d_out;

  char* p = (char*)d_ws;
  auto take = [&](size_t bytes) { char* r = p; p += (bytes + 255) & ~(size_t)255; return r; };
  unsigned char* xb8    = (unsigned char*)take((size_t)MTOK * EBD);        //  2 MB
  unsigned char* qk8    = (unsigned char*)take((size_t)MTOK * 2 * HE);     // 32 MB [4096][8192]
  unsigned char* vT8    = (unsigned char*)take((size_t)32 * EBD * SEQ);    // 16 MB [(b,h)][e][s]
  unsigned char* sc8    = (unsigned char*)take((size_t)32 * SEQ * SEQ);    // 32 MB exp-scores (fp32 partials overlay later)
  float*         lsum   = (float*)        take((size_t)32 * SEQ * 4);      // 128 KB row sums
  unsigned char* ao8    = (unsigned char*)take((size_t)MTOK * HE);         // 16 MB O*16
  float*         nF     = (float*)        take((size_t)MTOK * EBD * 4);    //  8 MB
  unsigned char* n8     = (unsigned char*)take((size_t)MTOK * EBD);        //  2 MB
  unsigned char* h8     = (unsigned char*)take((size_t)MTOK * FFD);        //  8 MB
  unsigned char* Wqkv8T = (unsigned char*)take((size_t)3 * HE * EBD);      //  6 MB [12288][512]
  unsigned char* Wo8T   = (unsigned char*)take((size_t)EBD * HE);          //  2 MB [512][4096]
  unsigned char* W18T   = (unsigned char*)take((size_t)FFD * EBD);         //  1 MB [2048][512]
  unsigned char* W28T   = (unsigned char*)take((size_t)EBD * FFD);         //  1 MB [512][2048]
  float* parts = (float*)sc8;   // 32 MB fp32 split-K partials (sc8 dead after attn@V)

  auto gemmf8 = [&](const unsigned char* A, const unsigned char* Bt, float* oF,
                    unsigned char* o8, unsigned char* vTo, const float* rdiv,
                    const float* bias_, float* lsum_,
                    int Mm, int Nn, int Kk, int lda_, int ldb_, int ldc_,
                    long long bAb, long long bAh, long long bBb, long long bBh,
                    long long bCb, long long bCh, int zdiv_, int batch,
                    float sc_, int mode_, int relu_, int vmode_) {
    dim3 g(Nn / 128, Mm / 128, batch);
    gemm_f8<<<g, dim3(256), 0, stream>>>(A, Bt, oF, o8, vTo, rdiv, bias_, lsum_,
        lda_, ldb_, ldc_, Kk, bAb, bAh, bBb, bBh, bCb, bCh, zdiv_, sc_, mode_, relu_, vmode_);
  };

  // --- preprocessing: x -> fp8 (+ zero lsum); weights -> fp8 transposed (scaled) ---
  cast_x_f8<<<dim3(MTOK * EBD / 16 / 256 + 1), dim3(256), 0, stream>>>(
      x, xb8, MTOK * EBD / 16, lsum);
  {
    WTList L;
    const float* ins[6] = {Wq, Wk, Wv, Wo, W1, W2};
    unsigned char* outs[6] = {Wqkv8T, Wqkv8T + (size_t)HE * EBD, Wqkv8T + (size_t)2 * HE * EBD,
                              Wo8T, W18T, W28T};
    float scs[6] = {8.f, 8.f, 8.f, 16.f, 8.f, 16.f};
    int Ks[6] = {EBD, EBD, EBD, HE, EBD, FFD};
    int Ns[6] = {HE, HE, HE, EBD, FFD, EBD};
    int acc = 0;
    for (int i = 0; i < 6; ++i) {
      L.in[i] = ins[i]; L.out[i] = outs[i]; L.scale[i] = scs[i];
      L.K[i] = Ks[i]; L.N[i] = Ns[i]; L.start[i] = acc;
      acc += (Ks[i] / 32) * (Ns[i] / 32);
    }
    L.start[6] = acc;
    transpose_cast_all<<<dim3(acc), dim3(32, 8), 0, stream>>>(L);
  }

  // --- fused QKV (fp8): q,k -> qk8 [4096][8192]; V -> vT8 transposed; scale 1/8 ---
  gemmf8(xb8, Wqkv8T, nullptr, qk8, vT8, nullptr, nullptr, nullptr,
         MTOK, 3 * HE, EBD, EBD, EBD, 2 * HE,
         0, 0, 0, 0, 0, 0, 64, 1, 0.125f, 0, 0, 1);

  // --- exp-scores = exp(q.k/sqrt(E)) fp8 + atomic row sums, batched over 32 (b,h) ---
  const float qs = 0.04419417382415922f;  // 1/sqrt(512)
  gemmf8(qk8, qk8 + HE, nullptr, sc8, nullptr, nullptr, nullptr, lsum,
         SEQ, SEQ, EBD, 2 * HE, 2 * HE, SEQ,
         (long long)SEQ * 2 * HE, EBD, (long long)SEQ * 2 * HE, EBD,
         (long long)8 * SEQ * SEQ, (long long)SEQ * SEQ, 8, 32, qs, 1, 0, 0);

  // --- O = (exp-scores @ v) * 16 / l, fp8 out into ao8 [token][h*512+e] ---
  gemmf8(sc8, vT8, nullptr, ao8, nullptr, lsum, nullptr, nullptr,
         SEQ, EBD, SEQ, SEQ, SEQ, HE,
         (long long)8 * SEQ * SEQ, (long long)SEQ * SEQ,
         (long long)8 * EBD * SEQ, (long long)EBD * SEQ,
         (long long)SEQ * HE, (long long)EBD, 8, 32, 16.0f, 2, 0, 0);

  // --- O16 @ Wo16^T, split-K x4 (K=4096) -> fp32 partials (scale 1/256); reduce + x + LN1 ---
  gemmf8(ao8, Wo8T, parts, nullptr, nullptr, nullptr, nullptr, nullptr,
         MTOK, EBD, 1024, HE, HE, EBD,
         0, 1024, 0, 1024, 0, (long long)MTOK * EBD, 64, 4, 1.0f / 256.0f, 3, 0, 0);
  reduce_ln<<<dim3(MTOK / 4), dim3(256), 0, stream>>>(parts, 4, x, nullptr, g1, b1, nF, n8);

  // --- FF1 (fp8): h = relu(n @ W1x8 /8 + c1) -> h8 ---
  gemmf8(n8, W18T, nullptr, h8, nullptr, nullptr, c1, nullptr,
         MTOK, FFD, EBD, EBD, EBD, FFD,
         0, 0, 0, 0, 0, 0, 64, 1, 0.125f, 0, 1, 0);

  // --- FF2 (fp8): h8 @ W2x16, split-K x4 (K=2048) -> partials (scale 1/16); reduce + c2 + nF + LN2 ---
  gemmf8(h8, W28T, parts, nullptr, nullptr, nullptr, nullptr, nullptr,
         MTOK, EBD, 512, FFD, FFD, EBD,
         0, 512, 0, 512, 0, (long long)MTOK * EBD, 64, 4, 1.0f / 16.0f, 3, 0, 0);
  reduce_ln<<<dim3(MTOK / 4), dim3(256), 0, stream>>>(parts, 4, nF, c2, g2, b2, out, nullptr);
}